// Round 1
// 358.934 us; speedup vs baseline: 1.0239x; 1.0239x over previous
//
#include <hip/hip_runtime.h>
#include <math.h>

#define N_BATCH 128
#define C_DIM   512
#define BLKSZ   46
#define T_DIM   (N_BATCH * BLKSZ)   // 5888
#define CI      256
#define EPS_BN  1e-5f
#define NCB     (T_DIM / 128)       // 46 col-blocks in the P GEMM

typedef __attribute__((ext_vector_type(8))) short bf16x8;
typedef __attribute__((ext_vector_type(4))) float f32x4;

__device__ __forceinline__ short f2bf(float f) {
    union { float f; unsigned u; } v; v.f = f;
    unsigned r = v.u + 0x7fffu + ((v.u >> 16) & 1u);
    return (short)(r >> 16);
}

__device__ __forceinline__ void gload16(const void* g, void* l) {
    __builtin_amdgcn_global_load_lds((__attribute__((address_space(1))) void*)g,
                                     (__attribute__((address_space(3))) void*)l,
                                     16, 0, 0);
}

// ---------------------------------------------------------------------------
// BN(inference)+ReLU+transpose: ori (N,C,46) fp32 -> feat (T, C) bf16.
// ---------------------------------------------------------------------------
__global__ __launch_bounds__(256) void bn_relu_kernel(
    const float* __restrict__ ori, const float* __restrict__ gamma,
    const float* __restrict__ beta, const float* __restrict__ mean,
    const float* __restrict__ var, short* __restrict__ feat)
{
    __shared__ short tile[256 * BLKSZ];
    const int n = blockIdx.y;
    const int c0 = blockIdx.x * 256;
    const int tid = threadIdx.x;
    for (int i = tid; i < 256 * BLKSZ; i += 256) {
        int cl = i / BLKSZ, b = i - cl * BLKSZ;
        int c = c0 + cl;
        float inv = gamma[c] * rsqrtf(var[c] + EPS_BN);
        float v = ori[((size_t)n * C_DIM + c) * BLKSZ + b] * inv + (beta[c] - mean[c] * inv);
        tile[cl * BLKSZ + b] = f2bf(fmaxf(v, 0.0f));
    }
    __syncthreads();
    for (int i = tid; i < BLKSZ * 256; i += 256) {
        int b = i >> 8, cl = i & 255;
        feat[(size_t)(n * BLKSZ + b) * C_DIM + c0 + cl] = tile[cl * BLKSZ + b];
    }
}

// ---------------------------------------------------------------------------
// Convert weights fp32->bf16: theta_w+phi_w packed into wcat (512 x 512),
// plus wg, wW. Block 0 additionally packs bcat = [theta_b; phi_b] (fp32).
// ---------------------------------------------------------------------------
__global__ __launch_bounds__(256) void cvt_kernel(
    const float* __restrict__ thw, const float* __restrict__ phw,
    const float* __restrict__ gw, const float* __restrict__ Ww,
    const float* __restrict__ thb, const float* __restrict__ phb,
    short* __restrict__ wcat, short* __restrict__ wg,
    short* __restrict__ wW, float* __restrict__ bcat)
{
    const int i = blockIdx.x * 256 + threadIdx.x;  // float4 index, 32768 per mat
    const float* src[4] = {thw, phw, gw, Ww};
    short* dst[4] = {wcat, wcat + 256 * 512, wg, wW};
    #pragma unroll
    for (int m = 0; m < 4; ++m) {
        float4 v = *(const float4*)(src[m] + (size_t)i * 4);
        short4 t = make_short4(f2bf(v.x), f2bf(v.y), f2bf(v.z), f2bf(v.w));
        *(short4*)(dst[m] + (size_t)i * 4) = t;
    }
    if (blockIdx.x == 0) {
        bcat[threadIdx.x] = thb[threadIdx.x];
        bcat[threadIdx.x + 256] = phb[threadIdx.x];
    }
}

// ---------------------------------------------------------------------------
// NT bf16 MFMA GEMM: C(M,Nn) = A(M,K) @ B(Nn,K)^T, BMxBN tile, BK=32,
// 4 waves (BM/64 x BN/64 arrangement of 64x64 wave blocks), 256 threads.
// ACVT=true: A is fp32 in global; during staging apply fused softmax
//   e = expf(v - m_row) * invZ_row, write e to fout (f_div_C, in place over
//   raw P), and feed bf16(e) to the MFMA. Each P element staged exactly once
//   (nx==1).
// EPI: 1 bf16 + col-bias; 2 bf16 + row-bias; 3 fp32 split-K partial;
//      4 fp32 + col-bias + ori^T add;
//      5 masked raw-P store + per-(row, colblock) softmax stats (max, expsum).
// ---------------------------------------------------------------------------
template <int EPI, bool ACVT, int BM, int BN>
__global__ __launch_bounds__(256, 2) void gemm_nt(
    const void* __restrict__ Avoid, const short* __restrict__ B,
    const float* __restrict__ bias, void* __restrict__ Cvoid,
    int M, int Nn, int K, int lda, int ldb, int nsplit,
    const float* __restrict__ ori,
    float* __restrict__ stats, const float* __restrict__ rowstat,
    float* __restrict__ fout)
{
    constexpr int NWC = BN / 64;
    __shared__ short As[BM * 32];
    __shared__ short Bs[BN * 32];
    const int tid = threadIdx.x;
    const int w = tid >> 6, lane = tid & 63;
    const int m0 = blockIdx.y * BM, n0 = blockIdx.x * BN;
    const int wr = w / NWC, wc = w % NWC;

    const int kper = K / 32 / nsplit;
    const int kt0 = blockIdx.z * kper, kt1 = kt0 + kper;

    f32x4 acc[4][4] = {};

    const int sr = tid >> 2;          // 0..63
    const int sc = (tid & 3) * 8;     // k offset of 16B chunk
    const short* Ab = (const short*)Avoid;
    const float* Af = (const float*)Avoid;

    // ACVT (fused-softmax) per-thread staging geometry + row stats, hoisted
    float rm = 0.f, rz = 0.f;
    int a_r = 0, a_c = 0;
    if constexpr (ACVT) {
        constexpr int EPT = BM / 8;     // fp32 elems per thread
        constexpr int TPR = 32 / EPT;   // threads per row
        a_r = tid / TPR;
        a_c = (tid % TPR) * EPT;
        float2 st = ((const float2*)rowstat)[m0 + a_r];
        rm = st.x; rz = st.y;
    }

    for (int kt = kt0; kt < kt1; ++kt) {
        const int k0 = kt * 32;
        if constexpr (!ACVT) {
            #pragma unroll
            for (int p = 0; p < BM / 64; ++p)
                gload16(Ab + (size_t)(m0 + p * 64 + sr) * lda + k0 + sc,
                        &As[(p * 64 + sr) * 32 + sc]);
        } else {
            constexpr int EPT = BM / 8;
            const float* src = Af + (size_t)(m0 + a_r) * lda + k0 + a_c;
            float* fd = fout + (size_t)(m0 + a_r) * lda + k0 + a_c;
            short tmp[EPT] __attribute__((aligned(16)));
            #pragma unroll
            for (int q = 0; q < EPT / 4; ++q) {
                float4 v = *(const float4*)(src + q * 4);
                float4 e;
                e.x = expf(v.x - rm) * rz;
                e.y = expf(v.y - rm) * rz;
                e.z = expf(v.z - rm) * rz;
                e.w = expf(v.w - rm) * rz;
                *(float4*)(fd + q * 4) = e;   // f_div_C output (exactly once)
                tmp[q * 4 + 0] = f2bf(e.x); tmp[q * 4 + 1] = f2bf(e.y);
                tmp[q * 4 + 2] = f2bf(e.z); tmp[q * 4 + 3] = f2bf(e.w);
            }
            #pragma unroll
            for (int q = 0; q < EPT / 8; ++q)
                *(bf16x8*)&As[a_r * 32 + a_c + q * 8] = *(bf16x8*)&tmp[q * 8];
        }
        #pragma unroll
        for (int p = 0; p < BN / 64; ++p)
            gload16(B + (size_t)(n0 + p * 64 + sr) * ldb + k0 + sc,
                    &Bs[(p * 64 + sr) * 32 + sc]);
        __syncthreads();

        bf16x8 af[4], bfr[4];
        #pragma unroll
        for (int i = 0; i < 4; ++i)
            af[i] = *(bf16x8*)&As[(wr * 64 + i * 16 + (lane & 15)) * 32 + (lane >> 4) * 8];
        #pragma unroll
        for (int j = 0; j < 4; ++j)
            bfr[j] = *(bf16x8*)&Bs[(wc * 64 + j * 16 + (lane & 15)) * 32 + (lane >> 4) * 8];
        #pragma unroll
        for (int i = 0; i < 4; ++i)
            #pragma unroll
            for (int j = 0; j < 4; ++j)
                acc[i][j] = __builtin_amdgcn_mfma_f32_16x16x32_bf16(af[i], bfr[j], acc[i][j], 0, 0, 0);
        __syncthreads();
    }

    // epilogue: C/D layout col=lane&15, row=(lane>>4)*4+reg  [m89-verified]
    const int col = lane & 15, rowq = lane >> 4;

    if constexpr (EPI == 5) {
        // masked raw-P store + flash-style per-(row, colblock) stats
        __shared__ float sm[NWC][BM];
        __shared__ float ss[NWC][BM];
        int cbj[4];
        #pragma unroll
        for (int j = 0; j < 4; ++j)
            cbj[j] = (n0 + wc * 64 + j * 16 + col) / BLKSZ;
        #pragma unroll
        for (int i = 0; i < 4; ++i) {
            #pragma unroll
            for (int r = 0; r < 4; ++r) {
                const int trow = wr * 64 + i * 16 + rowq * 4 + r;
                const int grow = m0 + trow;
                const int rb = grow / BLKSZ;
                float vj[4];
                float vmax = -1e30f;
                #pragma unroll
                for (int j = 0; j < 4; ++j) {
                    float v = acc[i][j][r];
                    if (cbj[j] == rb) v = -30000.0f;   // mask: exp underflows to 0
                    vj[j] = v;
                    ((float*)Cvoid)[(size_t)grow * Nn + (n0 + wc * 64 + j * 16 + col)] = v;
                    vmax = fmaxf(vmax, v);
                }
                #pragma unroll
                for (int off = 1; off < 16; off <<= 1)
                    vmax = fmaxf(vmax, __shfl_xor(vmax, off));
                float s = 0.f;
                #pragma unroll
                for (int j = 0; j < 4; ++j) s += expf(vj[j] - vmax);
                #pragma unroll
                for (int off = 1; off < 16; off <<= 1)
                    s += __shfl_xor(s, off);
                if (col == 0) { sm[wc][trow] = vmax; ss[wc][trow] = s; }
            }
        }
        __syncthreads();
        if (tid < BM) {
            const float ma = sm[0][tid], mb = sm[1][tid];
            const float mx = fmaxf(ma, mb);
            const float S = ss[0][tid] * expf(ma - mx) + ss[1][tid] * expf(mb - mx);
            ((float2*)stats)[(size_t)blockIdx.x * M + (m0 + tid)] = make_float2(mx, S);
        }
    } else {
        #pragma unroll
        for (int i = 0; i < 4; ++i) {
            #pragma unroll
            for (int j = 0; j < 4; ++j) {
                #pragma unroll
                for (int r = 0; r < 4; ++r) {
                    const int grow = m0 + wr * 64 + i * 16 + rowq * 4 + r;
                    const int gcol = n0 + wc * 64 + j * 16 + col;
                    const float v = acc[i][j][r];
                    if (EPI == 1) {
                        ((short*)Cvoid)[(size_t)grow * Nn + gcol] = f2bf(v + bias[gcol]);
                    } else if (EPI == 2) {
                        ((short*)Cvoid)[(size_t)grow * Nn + gcol] = f2bf(v + bias[grow]);
                    } else if (EPI == 3) {
                        ((float*)Cvoid)[(size_t)blockIdx.z * M * Nn + (size_t)grow * Nn + gcol] = v;
                    } else {
                        const int nb = grow / BLKSZ, bb = grow - nb * BLKSZ;
                        ((float*)Cvoid)[(size_t)grow * Nn + gcol] =
                            v + bias[gcol] + ori[((size_t)nb * C_DIM + gcol) * BLKSZ + bb];
                    }
                }
            }
        }
    }
}

// ---------------------------------------------------------------------------
// Combine per-colblock stats (NCB x T float2: max, expsum) -> per-row
// (max, 1/Z) via online merge. 23 blocks x 256 threads, one row per thread.
// ---------------------------------------------------------------------------
__global__ __launch_bounds__(256) void combine_stats_kernel(
    const float* __restrict__ stats, float* __restrict__ rowstat)
{
    const int row = blockIdx.x * 256 + threadIdx.x;
    float m = -1e30f, Z = 0.f;
    for (int cb = 0; cb < NCB; ++cb) {
        float2 p = ((const float2*)stats)[(size_t)cb * T_DIM + row];
        float nm = fmaxf(m, p.x);
        Z = Z * expf(m - nm) + p.y * expf(p.x - nm);
        m = nm;
    }
    ((float2*)rowstat)[row] = make_float2(m, 1.0f / Z);
}

// ---------------------------------------------------------------------------
// Reduce split-K partials (ns, T, CI) fp32 -> y (T, CI) bf16.
// ---------------------------------------------------------------------------
__global__ __launch_bounds__(256) void reduce_y_kernel(
    const float* __restrict__ part, short* __restrict__ y, int ns)
{
    const size_t i = (size_t)blockIdx.x * 256 + threadIdx.x;  // float4 index
    float4 s = *(const float4*)(part + i * 4);
    for (int z = 1; z < ns; ++z) {
        float4 v = *(const float4*)(part + (size_t)z * T_DIM * CI + i * 4);
        s.x += v.x; s.y += v.y; s.z += v.z; s.w += v.w;
    }
    short4 t = make_short4(f2bf(s.x), f2bf(s.y), f2bf(s.z), f2bf(s.w));
    *(short4*)(y + i * 4) = t;
}

// ---------------------------------------------------------------------------
extern "C" void kernel_launch(void* const* d_in, const int* in_sizes, int n_in,
                              void* d_out, int out_size, void* d_ws, size_t ws_size,
                              hipStream_t stream)
{
    const float* ori     = (const float*)d_in[0];
    const float* gamma   = (const float*)d_in[1];
    const float* beta    = (const float*)d_in[2];
    const float* mean    = (const float*)d_in[3];
    const float* var     = (const float*)d_in[4];
    const float* theta_w = (const float*)d_in[5];
    const float* theta_b = (const float*)d_in[6];
    const float* phi_w   = (const float*)d_in[7];
    const float* phi_b   = (const float*)d_in[8];
    const float* g_w     = (const float*)d_in[9];
    const float* g_b     = (const float*)d_in[10];
    const float* W_w     = (const float*)d_in[11];
    const float* W_b     = (const float*)d_in[12];

    float* out = (float*)d_out;                    // att_fea (T, C), then f_div_C (T, T)
    float* P   = out + (size_t)T_DIM * C_DIM;      // raw scores -> f_div_C in place

    char* wsb = (char*)d_ws;
    short* feat = (short*)wsb;  wsb += (size_t)T_DIM * C_DIM * 2;   // 6.03 MB
    short* xcat = (short*)wsb;  wsb += (size_t)T_DIM * 512 * 2;     // 6.03 MB (xth|xph)
    short* gxT  = (short*)wsb;  wsb += (size_t)CI * T_DIM * 2;      // 3.01 MB (CI, T)
    short* wcat = (short*)wsb;  wsb += (size_t)512 * C_DIM * 2;     // 0.52 MB
    short* wg   = (short*)wsb;  wsb += (size_t)CI * C_DIM * 2;
    short* wW   = (short*)wsb;  wsb += (size_t)C_DIM * CI * 2;
    float* bcat = (float*)wsb;  wsb += 512 * 4;
    short* ybf  = (short*)wsb;  wsb += (size_t)T_DIM * CI * 2;      // 3.01 MB
    float* rowstat = (float*)wsb; wsb += (size_t)T_DIM * 8;         // 47 KB
    float* ypart= (float*)wsb;                                      // ns * 6.03 MB
    // stats (NCB x T float2 = 2.17 MB) aliases ypart: consumed by
    // combine_stats before the split-K GEMM writes ypart.
    float* stats = ypart;

    const size_t base = (size_t)((char*)ypart - (char*)d_ws);
    const int ns = (ws_size >= base + 4u * (size_t)T_DIM * CI * 4u) ? 4 : 2;

    // 1) BN + ReLU + transpose -> feat bf16; weights -> bf16 (+ packed bias)
    bn_relu_kernel<<<dim3(2, 128), 256, 0, stream>>>(ori, gamma, beta, mean, var, feat);
    cvt_kernel<<<128, 256, 0, stream>>>(theta_w, phi_w, g_w, W_w, theta_b, phi_b,
                                        wcat, wg, wW, bcat);

    // 2) xcat = feat @ wcat^T + bcat  (M=T, Nn=512, K=512) -> [xth | xph] bf16
    gemm_nt<1, false, 128, 128><<<dim3(4, T_DIM / 128), 256, 0, stream>>>(
        feat, wcat, bcat, xcat, T_DIM, 512, C_DIM, C_DIM, C_DIM, 1, nullptr,
        nullptr, nullptr, nullptr);

    // 3) gxT = wg @ feat^T + g_b(row)  (M=CI, Nn=T, K=C) bf16
    gemm_nt<2, false, 128, 128><<<dim3(T_DIM / 128, CI / 128), 256, 0, stream>>>(
        wg, feat, g_b, gxT, CI, T_DIM, C_DIM, C_DIM, C_DIM, 1, nullptr,
        nullptr, nullptr, nullptr);

    // 4) P = xth @ xph^T (M=Nn=T, K=CI), masked raw scores + softmax stats
    gemm_nt<5, false, 128, 128><<<dim3(T_DIM / 128, T_DIM / 128), 256, 0, stream>>>(
        xcat, xcat + CI, nullptr, P, T_DIM, T_DIM, CI, 512, 512, 1, nullptr,
        stats, nullptr, nullptr);

    // 5) per-row (max, 1/Z) from per-colblock stats
    combine_stats_kernel<<<T_DIM / 256, 256, 0, stream>>>(stats, rowstat);

    // 6) ypart[z] = softmax(P) @ gxT^T with softmax fused into staging;
    //    writes f_div_C in place over raw P (each element staged once).
    gemm_nt<3, true, 64, 256><<<dim3(1, T_DIM / 64, ns), 256, 0, stream>>>(
        P, gxT, nullptr, ypart, T_DIM, CI, T_DIM, T_DIM, T_DIM, ns, nullptr,
        nullptr, rowstat, P);
    reduce_y_kernel<<<(T_DIM * CI / 4) / 256, 256, 0, stream>>>(ypart, ybf, ns);

    // 7) att_fea = y @ wW^T + W_b + ori^T  (M=T, Nn=C, K=CI), fp32 out
    gemm_nt<4, false, 128, 128><<<dim3(C_DIM / 128, T_DIM / 128), 256, 0, stream>>>(
        ybf, wW, W_b, out, T_DIM, C_DIM, CI, CI, CI, 1, ori,
        nullptr, nullptr, nullptr);
}

// Round 2
// 350.468 us; speedup vs baseline: 1.0487x; 1.0242x over previous
//
#include <hip/hip_runtime.h>
#include <math.h>

#define N_BATCH 128
#define C_DIM   512
#define BLKSZ   46
#define T_DIM   (N_BATCH * BLKSZ)   // 5888
#define CI      256
#define EPS_BN  1e-5f
#define NCB     (T_DIM / 128)       // 46 col-blocks in the P GEMM

typedef __attribute__((ext_vector_type(8))) short bf16x8;
typedef __attribute__((ext_vector_type(4))) float f32x4;

__device__ __forceinline__ short f2bf(float f) {
    union { float f; unsigned u; } v; v.f = f;
    unsigned r = v.u + 0x7fffu + ((v.u >> 16) & 1u);
    return (short)(r >> 16);
}

__device__ __forceinline__ float h2f(unsigned short h) {
    _Float16 x; __builtin_memcpy(&x, &h, 2); return (float)x;
}
__device__ __forceinline__ unsigned short f2h(float f) {
    _Float16 x = (_Float16)f; unsigned short u; __builtin_memcpy(&u, &x, 2); return u;
}

__device__ __forceinline__ void gload16(const void* g, void* l) {
    __builtin_amdgcn_global_load_lds((__attribute__((address_space(1))) void*)g,
                                     (__attribute__((address_space(3))) void*)l,
                                     16, 0, 0);
}

// ---------------------------------------------------------------------------
// BN(inference)+ReLU+transpose: ori (N,C,46) fp32 -> feat (T, C) bf16.
// ---------------------------------------------------------------------------
__global__ __launch_bounds__(256) void bn_relu_kernel(
    const float* __restrict__ ori, const float* __restrict__ gamma,
    const float* __restrict__ beta, const float* __restrict__ mean,
    const float* __restrict__ var, short* __restrict__ feat)
{
    __shared__ short tile[256 * BLKSZ];
    const int n = blockIdx.y;
    const int c0 = blockIdx.x * 256;
    const int tid = threadIdx.x;
    for (int i = tid; i < 256 * BLKSZ; i += 256) {
        int cl = i / BLKSZ, b = i - cl * BLKSZ;
        int c = c0 + cl;
        float inv = gamma[c] * rsqrtf(var[c] + EPS_BN);
        float v = ori[((size_t)n * C_DIM + c) * BLKSZ + b] * inv + (beta[c] - mean[c] * inv);
        tile[cl * BLKSZ + b] = f2bf(fmaxf(v, 0.0f));
    }
    __syncthreads();
    for (int i = tid; i < BLKSZ * 256; i += 256) {
        int b = i >> 8, cl = i & 255;
        feat[(size_t)(n * BLKSZ + b) * C_DIM + c0 + cl] = tile[cl * BLKSZ + b];
    }
}

// ---------------------------------------------------------------------------
// Convert weights fp32->bf16: theta_w+phi_w packed into wcat (512 x 512),
// plus wg, wW. Block 0 additionally packs bcat = [theta_b; phi_b] (fp32).
// ---------------------------------------------------------------------------
__global__ __launch_bounds__(256) void cvt_kernel(
    const float* __restrict__ thw, const float* __restrict__ phw,
    const float* __restrict__ gw, const float* __restrict__ Ww,
    const float* __restrict__ thb, const float* __restrict__ phb,
    short* __restrict__ wcat, short* __restrict__ wg,
    short* __restrict__ wW, float* __restrict__ bcat)
{
    const int i = blockIdx.x * 256 + threadIdx.x;  // float4 index, 32768 per mat
    const float* src[4] = {thw, phw, gw, Ww};
    short* dst[4] = {wcat, wcat + 256 * 512, wg, wW};
    #pragma unroll
    for (int m = 0; m < 4; ++m) {
        float4 v = *(const float4*)(src[m] + (size_t)i * 4);
        short4 t = make_short4(f2bf(v.x), f2bf(v.y), f2bf(v.z), f2bf(v.w));
        *(short4*)(dst[m] + (size_t)i * 4) = t;
    }
    if (blockIdx.x == 0) {
        bcat[threadIdx.x] = thb[threadIdx.x];
        bcat[threadIdx.x + 256] = phb[threadIdx.x];
    }
}

// ---------------------------------------------------------------------------
// NT bf16 MFMA GEMM: C(M,Nn) = A(M,K) @ B(Nn,K)^T, BMxBN tile, BK=32,
// 4 waves, 256 threads. Wave grid: NWC = BN/64 cols, NWR = 4/NWC rows;
// wave tile = (BM/NWR) x 64, MI = BM/NWR/16 row-fragments.
// ACVT: 0 none (A bf16, global_load_lds);
//       1 A fp32, fused softmax e=expf(v-m)*invZ, write e to fout, bf16->LDS;
//       2 A fp16, same fused softmax.
// EPI: 1 bf16 + col-bias; 2 bf16 + row-bias; 3 fp32 split-K partial;
//      4 fp32 + col-bias + ori^T add;
//      5 masked fp32 P store + per-(row,colblock) stats (max, expsum);
//      6 masked fp16 P store + stats (stats from the fp16-rounded values).
// ---------------------------------------------------------------------------
template <int EPI, int ACVT, int BM, int BN>
__global__ __launch_bounds__(256, 2) void gemm_nt(
    const void* __restrict__ Avoid, const short* __restrict__ B,
    const float* __restrict__ bias, void* __restrict__ Cvoid,
    int M, int Nn, int K, int lda, int ldb, int nsplit,
    const float* __restrict__ ori,
    float* __restrict__ stats, const float* __restrict__ rowstat,
    float* __restrict__ fout)
{
    constexpr int NWC = BN / 64;
    constexpr int NWR = 4 / NWC;
    constexpr int MI  = BM / (NWR * 16);
    static_assert((EPI != 5 && EPI != 6) || NWC == 2, "stats epilogue assumes NWC==2");
    __shared__ short As[BM * 32];
    __shared__ short Bs[BN * 32];
    const int tid = threadIdx.x;
    const int w = tid >> 6, lane = tid & 63;
    const int m0 = blockIdx.y * BM, n0 = blockIdx.x * BN;
    const int wr = w / NWC, wc = w % NWC;
    const int wrow = wr * (MI * 16);

    const int kper = K / 32 / nsplit;
    const int kt0 = blockIdx.z * kper, kt1 = kt0 + kper;

    f32x4 acc[MI][4] = {};

    const int sr = tid >> 2;          // 0..63
    const int sc = (tid & 3) * 8;     // k offset of 16B chunk
    const short* Ab = (const short*)Avoid;
    const float* Af = (const float*)Avoid;
    const unsigned short* Ah = (const unsigned short*)Avoid;

    // ACVT (fused-softmax) per-thread staging geometry + row stats, hoisted
    float rm = 0.f, rz = 0.f;
    int a_r = 0, a_c = 0;
    if constexpr (ACVT != 0) {
        constexpr int EPT = BM * 32 / 256;   // elems per thread
        constexpr int TPR = 32 / EPT;        // threads per row
        a_r = tid / TPR;
        a_c = (tid % TPR) * EPT;
        float2 st = ((const float2*)rowstat)[m0 + a_r];
        rm = st.x; rz = st.y;
    }

    for (int kt = kt0; kt < kt1; ++kt) {
        const int k0 = kt * 32;
        if constexpr (ACVT == 0) {
            #pragma unroll
            for (int p = 0; p < BM / 64; ++p)
                gload16(Ab + (size_t)(m0 + p * 64 + sr) * lda + k0 + sc,
                        &As[(p * 64 + sr) * 32 + sc]);
        } else {
            constexpr int EPT = BM * 32 / 256;
            const int k0c = k0 + a_c;
            float* fd = fout + (size_t)(m0 + a_r) * lda + k0c;
            short tmp[EPT] __attribute__((aligned(16)));
            #pragma unroll
            for (int q = 0; q < EPT / 4; ++q) {
                float4 e;
                if constexpr (ACVT == 1) {
                    float4 v = *(const float4*)(Af + (size_t)(m0 + a_r) * lda + k0c + q * 4);
                    e.x = expf(v.x - rm) * rz;
                    e.y = expf(v.y - rm) * rz;
                    e.z = expf(v.z - rm) * rz;
                    e.w = expf(v.w - rm) * rz;
                } else {
                    ushort4 hv = *(const ushort4*)(Ah + (size_t)(m0 + a_r) * lda + k0c + q * 4);
                    e.x = expf(h2f(hv.x) - rm) * rz;
                    e.y = expf(h2f(hv.y) - rm) * rz;
                    e.z = expf(h2f(hv.z) - rm) * rz;
                    e.w = expf(h2f(hv.w) - rm) * rz;
                }
                *(float4*)(fd + q * 4) = e;   // f_div_C output (exactly once)
                tmp[q * 4 + 0] = f2bf(e.x); tmp[q * 4 + 1] = f2bf(e.y);
                tmp[q * 4 + 2] = f2bf(e.z); tmp[q * 4 + 3] = f2bf(e.w);
            }
            #pragma unroll
            for (int q = 0; q < EPT / 4; ++q)
                *(short4*)&As[a_r * 32 + a_c + q * 4] = *(short4*)&tmp[q * 4];
        }
        #pragma unroll
        for (int p = 0; p < BN / 64; ++p)
            gload16(B + (size_t)(n0 + p * 64 + sr) * ldb + k0 + sc,
                    &Bs[(p * 64 + sr) * 32 + sc]);
        __syncthreads();

        bf16x8 af[MI], bfr[4];
        #pragma unroll
        for (int i = 0; i < MI; ++i)
            af[i] = *(bf16x8*)&As[(wrow + i * 16 + (lane & 15)) * 32 + (lane >> 4) * 8];
        #pragma unroll
        for (int j = 0; j < 4; ++j)
            bfr[j] = *(bf16x8*)&Bs[(wc * 64 + j * 16 + (lane & 15)) * 32 + (lane >> 4) * 8];
        #pragma unroll
        for (int i = 0; i < MI; ++i)
            #pragma unroll
            for (int j = 0; j < 4; ++j)
                acc[i][j] = __builtin_amdgcn_mfma_f32_16x16x32_bf16(af[i], bfr[j], acc[i][j], 0, 0, 0);
        __syncthreads();
    }

    // epilogue: C/D layout col=lane&15, row=(lane>>4)*4+reg  [m89-verified]
    const int col = lane & 15, rowq = lane >> 4;

    if constexpr (EPI == 5 || EPI == 6) {
        // masked raw-P store + flash-style per-(row, colblock) stats
        __shared__ float sm[NWC][BM];
        __shared__ float ss[NWC][BM];
        int cbj[4];
        #pragma unroll
        for (int j = 0; j < 4; ++j)
            cbj[j] = (n0 + wc * 64 + j * 16 + col) / BLKSZ;
        #pragma unroll
        for (int i = 0; i < MI; ++i) {
            #pragma unroll
            for (int r = 0; r < 4; ++r) {
                const int trow = wrow + i * 16 + rowq * 4 + r;
                const int grow = m0 + trow;
                const int rb = grow / BLKSZ;
                float vj[4];
                float vmax = -1e30f;
                #pragma unroll
                for (int j = 0; j < 4; ++j) {
                    float v = acc[i][j][r];
                    if (cbj[j] == rb) v = -30000.0f;   // mask: exp underflows to 0
                    const size_t idx = (size_t)grow * Nn + (n0 + wc * 64 + j * 16 + col);
                    if constexpr (EPI == 6) {
                        unsigned short hh = f2h(v);
                        ((unsigned short*)Cvoid)[idx] = hh;
                        v = h2f(hh);       // stats from rounded value
                    } else {
                        ((float*)Cvoid)[idx] = v;
                    }
                    vj[j] = v;
                    vmax = fmaxf(vmax, v);
                }
                #pragma unroll
                for (int off = 1; off < 16; off <<= 1)
                    vmax = fmaxf(vmax, __shfl_xor(vmax, off));
                float s = 0.f;
                #pragma unroll
                for (int j = 0; j < 4; ++j) s += expf(vj[j] - vmax);
                #pragma unroll
                for (int off = 1; off < 16; off <<= 1)
                    s += __shfl_xor(s, off);
                if (col == 0) { sm[wc][trow] = vmax; ss[wc][trow] = s; }
            }
        }
        __syncthreads();
        if (tid < BM) {
            const float ma = sm[0][tid], mb = sm[1][tid];
            const float mx = fmaxf(ma, mb);
            const float S = ss[0][tid] * expf(ma - mx) + ss[1][tid] * expf(mb - mx);
            ((float2*)stats)[(size_t)blockIdx.x * M + (m0 + tid)] = make_float2(mx, S);
        }
    } else {
        #pragma unroll
        for (int i = 0; i < MI; ++i) {
            #pragma unroll
            for (int j = 0; j < 4; ++j) {
                #pragma unroll
                for (int r = 0; r < 4; ++r) {
                    const int grow = m0 + wrow + i * 16 + rowq * 4 + r;
                    const int gcol = n0 + wc * 64 + j * 16 + col;
                    const float v = acc[i][j][r];
                    if (EPI == 1) {
                        ((short*)Cvoid)[(size_t)grow * Nn + gcol] = f2bf(v + bias[gcol]);
                    } else if (EPI == 2) {
                        ((short*)Cvoid)[(size_t)grow * Nn + gcol] = f2bf(v + bias[grow]);
                    } else if (EPI == 3) {
                        ((float*)Cvoid)[(size_t)blockIdx.z * M * Nn + (size_t)grow * Nn + gcol] = v;
                    } else {
                        const int nb = grow / BLKSZ, bb = grow - nb * BLKSZ;
                        ((float*)Cvoid)[(size_t)grow * Nn + gcol] =
                            v + bias[gcol] + ori[((size_t)nb * C_DIM + gcol) * BLKSZ + bb];
                    }
                }
            }
        }
    }
}

// ---------------------------------------------------------------------------
// Combine per-colblock stats (NCB x T float2: max, expsum) -> per-row
// (max, 1/Z) via online merge. 23 blocks x 256 threads, one row per thread.
// ---------------------------------------------------------------------------
__global__ __launch_bounds__(256) void combine_stats_kernel(
    const float* __restrict__ stats, float* __restrict__ rowstat)
{
    const int row = blockIdx.x * 256 + threadIdx.x;
    float m = -1e30f, Z = 0.f;
    for (int cb = 0; cb < NCB; ++cb) {
        float2 p = ((const float2*)stats)[(size_t)cb * T_DIM + row];
        float nm = fmaxf(m, p.x);
        Z = Z * expf(m - nm) + p.y * expf(p.x - nm);
        m = nm;
    }
    ((float2*)rowstat)[row] = make_float2(m, 1.0f / Z);
}

// ---------------------------------------------------------------------------
// Reduce split-K partials (ns, T, CI) fp32 -> y (T, CI) bf16.
// ---------------------------------------------------------------------------
__global__ __launch_bounds__(256) void reduce_y_kernel(
    const float* __restrict__ part, short* __restrict__ y, int ns)
{
    const size_t i = (size_t)blockIdx.x * 256 + threadIdx.x;  // float4 index
    float4 s = *(const float4*)(part + i * 4);
    for (int z = 1; z < ns; ++z) {
        float4 v = *(const float4*)(part + (size_t)z * T_DIM * CI + i * 4);
        s.x += v.x; s.y += v.y; s.z += v.z; s.w += v.w;
    }
    short4 t = make_short4(f2bf(s.x), f2bf(s.y), f2bf(s.z), f2bf(s.w));
    *(short4*)(y + i * 4) = t;
}

// ---------------------------------------------------------------------------
extern "C" void kernel_launch(void* const* d_in, const int* in_sizes, int n_in,
                              void* d_out, int out_size, void* d_ws, size_t ws_size,
                              hipStream_t stream)
{
    const float* ori     = (const float*)d_in[0];
    const float* gamma   = (const float*)d_in[1];
    const float* beta    = (const float*)d_in[2];
    const float* mean    = (const float*)d_in[3];
    const float* var     = (const float*)d_in[4];
    const float* theta_w = (const float*)d_in[5];
    const float* theta_b = (const float*)d_in[6];
    const float* phi_w   = (const float*)d_in[7];
    const float* phi_b   = (const float*)d_in[8];
    const float* g_w     = (const float*)d_in[9];
    const float* g_b     = (const float*)d_in[10];
    const float* W_w     = (const float*)d_in[11];
    const float* W_b     = (const float*)d_in[12];

    float* out = (float*)d_out;                    // att_fea (T, C), then f_div_C (T, T)
    float* P   = out + (size_t)T_DIM * C_DIM;      // f_div_C region

    char* wsb = (char*)d_ws;
    short* feat = (short*)wsb;  wsb += (size_t)T_DIM * C_DIM * 2;   // 6.03 MB
    short* xcat = (short*)wsb;  wsb += (size_t)T_DIM * 512 * 2;     // 6.03 MB (xth|xph)
    short* gxT  = (short*)wsb;  wsb += (size_t)CI * T_DIM * 2;      // 3.01 MB (CI, T)
    short* wcat = (short*)wsb;  wsb += (size_t)512 * C_DIM * 2;     // 0.52 MB
    short* wg   = (short*)wsb;  wsb += (size_t)CI * C_DIM * 2;
    short* wW   = (short*)wsb;  wsb += (size_t)C_DIM * CI * 2;
    float* bcat = (float*)wsb;  wsb += 512 * 4;
    short* ybf  = (short*)wsb;  wsb += (size_t)T_DIM * CI * 2;      // 3.01 MB
    float* rowstat = (float*)wsb; wsb += (size_t)T_DIM * 8;         // 47 KB

    const size_t base   = (size_t)(wsb - (char*)d_ws);
    const size_t p16sz  = (size_t)T_DIM * T_DIM * 2;                // 69.3 MB
    const size_t ypsz4  = 4u * (size_t)T_DIM * CI * 4u;             // 24.1 MB
    const bool bigws = ws_size >= base + p16sz + ypsz4;

    // 1) BN + ReLU + transpose -> feat bf16; weights -> bf16 (+ packed bias)
    bn_relu_kernel<<<dim3(2, 128), 256, 0, stream>>>(ori, gamma, beta, mean, var, feat);
    cvt_kernel<<<128, 256, 0, stream>>>(theta_w, phi_w, g_w, W_w, theta_b, phi_b,
                                        wcat, wg, wW, bcat);

    // 2) xcat = feat @ wcat^T + bcat  (M=T, Nn=512, K=512) -> [xth | xph] bf16
    gemm_nt<1, 0, 128, 128><<<dim3(4, T_DIM / 128), 256, 0, stream>>>(
        feat, wcat, bcat, xcat, T_DIM, 512, C_DIM, C_DIM, C_DIM, 1, nullptr,
        nullptr, nullptr, nullptr);

    // 3) gxT = wg @ feat^T + g_b(row)  (M=CI, Nn=T, K=C) bf16
    gemm_nt<2, 0, 128, 128><<<dim3(T_DIM / 128, CI / 128), 256, 0, stream>>>(
        wg, feat, g_b, gxT, CI, T_DIM, C_DIM, C_DIM, C_DIM, 1, nullptr,
        nullptr, nullptr, nullptr);

    if (bigws) {
        // --- fp16 raw-P path ---
        unsigned short* p16 = (unsigned short*)wsb;
        float* ypart = (float*)(wsb + p16sz);
        float* stats = ypart;   // 2.17 MB alias, consumed before ypart written

        // 4) P16 = mask(xth @ xph^T) fp16 + softmax stats
        gemm_nt<6, 0, 128, 128><<<dim3(T_DIM / 128, T_DIM / 128), 256, 0, stream>>>(
            xcat, xcat + CI, nullptr, p16, T_DIM, T_DIM, CI, 512, 512, 1, nullptr,
            stats, nullptr, nullptr);
        // 5) per-row (max, 1/Z)
        combine_stats_kernel<<<T_DIM / 256, 256, 0, stream>>>(stats, rowstat);
        // 6) ypart[z] = softmax(P16) @ gxT^T, softmax fused into staging,
        //    writes f_div_C fp32 to out region (each element staged once)
        gemm_nt<3, 2, 32, 256><<<dim3(1, T_DIM / 32, 4), 256, 0, stream>>>(
            p16, gxT, nullptr, ypart, T_DIM, CI, T_DIM, T_DIM, T_DIM, 4, nullptr,
            nullptr, rowstat, P);
        reduce_y_kernel<<<(T_DIM * CI / 4) / 256, 256, 0, stream>>>(ypart, ybf, 4);
    } else {
        // --- fallback: fp32 raw P in out region, softmax in place ---
        float* ypart = (float*)wsb;
        float* stats = ypart;
        const int ns = (ws_size >= base + ypsz4) ? 4 : 2;

        gemm_nt<5, 0, 128, 128><<<dim3(T_DIM / 128, T_DIM / 128), 256, 0, stream>>>(
            xcat, xcat + CI, nullptr, P, T_DIM, T_DIM, CI, 512, 512, 1, nullptr,
            stats, nullptr, nullptr);
        combine_stats_kernel<<<T_DIM / 256, 256, 0, stream>>>(stats, rowstat);
        gemm_nt<3, 1, 32, 256><<<dim3(1, T_DIM / 32, ns), 256, 0, stream>>>(
            P, gxT, nullptr, ypart, T_DIM, CI, T_DIM, T_DIM, T_DIM, ns, nullptr,
            nullptr, rowstat, P);
        reduce_y_kernel<<<(T_DIM * CI / 4) / 256, 256, 0, stream>>>(ypart, ybf, ns);
    }

    // 7) att_fea = y @ wW^T + W_b + ori^T  (M=T, Nn=C, K=CI), fp32 out
    gemm_nt<4, 0, 128, 128><<<dim3(C_DIM / 128, T_DIM / 128), 256, 0, stream>>>(
        ybf, wW, W_b, out, T_DIM, C_DIM, CI, CI, CI, 1, ori,
        nullptr, nullptr, nullptr);
}

// Round 3
// 340.564 us; speedup vs baseline: 1.0792x; 1.0291x over previous
//
#include <hip/hip_runtime.h>
#include <math.h>

#define N_BATCH 128
#define C_DIM   512
#define BLKSZ   46
#define T_DIM   (N_BATCH * BLKSZ)   // 5888
#define CI      256
#define EPS_BN  1e-5f
#define NCB     (T_DIM / 128)       // 46 col-blocks in the P GEMM

typedef __attribute__((ext_vector_type(8))) short bf16x8;
typedef __attribute__((ext_vector_type(4))) float f32x4;

__device__ __forceinline__ short f2bf(float f) {
    union { float f; unsigned u; } v; v.f = f;
    unsigned r = v.u + 0x7fffu + ((v.u >> 16) & 1u);
    return (short)(r >> 16);
}

__device__ __forceinline__ float h2f(unsigned short h) {
    _Float16 x; __builtin_memcpy(&x, &h, 2); return (float)x;
}
__device__ __forceinline__ unsigned short f2h(float f) {
    _Float16 x = (_Float16)f; unsigned short u; __builtin_memcpy(&u, &x, 2); return u;
}

__device__ __forceinline__ void gload16(const void* g, void* l) {
    __builtin_amdgcn_global_load_lds((__attribute__((address_space(1))) void*)g,
                                     (__attribute__((address_space(3))) void*)l,
                                     16, 0, 0);
}

template <int A> struct avec_sel { using t = float4; };
template <> struct avec_sel<2> { using t = ushort4; };

// ---------------------------------------------------------------------------
// BN(inference)+ReLU+transpose: ori (N,C,46) fp32 -> feat (T, C) bf16.
// ---------------------------------------------------------------------------
__global__ __launch_bounds__(256) void bn_relu_kernel(
    const float* __restrict__ ori, const float* __restrict__ gamma,
    const float* __restrict__ beta, const float* __restrict__ mean,
    const float* __restrict__ var, short* __restrict__ feat)
{
    __shared__ short tile[256 * BLKSZ];
    const int n = blockIdx.y;
    const int c0 = blockIdx.x * 256;
    const int tid = threadIdx.x;
    for (int i = tid; i < 256 * BLKSZ; i += 256) {
        int cl = i / BLKSZ, b = i - cl * BLKSZ;
        int c = c0 + cl;
        float inv = gamma[c] * rsqrtf(var[c] + EPS_BN);
        float v = ori[((size_t)n * C_DIM + c) * BLKSZ + b] * inv + (beta[c] - mean[c] * inv);
        tile[cl * BLKSZ + b] = f2bf(fmaxf(v, 0.0f));
    }
    __syncthreads();
    for (int i = tid; i < BLKSZ * 256; i += 256) {
        int b = i >> 8, cl = i & 255;
        feat[(size_t)(n * BLKSZ + b) * C_DIM + c0 + cl] = tile[cl * BLKSZ + b];
    }
}

// ---------------------------------------------------------------------------
// Convert weights fp32->bf16: theta_w+phi_w+g_w packed into wall (768 x 512),
// plus wW. Block 0 additionally packs bcat = [theta_b; phi_b; g_b] (fp32).
// ---------------------------------------------------------------------------
__global__ __launch_bounds__(256) void cvt_kernel(
    const float* __restrict__ thw, const float* __restrict__ phw,
    const float* __restrict__ gw, const float* __restrict__ Ww,
    const float* __restrict__ thb, const float* __restrict__ phb,
    const float* __restrict__ gb,
    short* __restrict__ wall, short* __restrict__ wW, float* __restrict__ bcat)
{
    const int i = blockIdx.x * 256 + threadIdx.x;  // float4 index, 32768 per mat
    const float* src[4] = {thw, phw, gw, Ww};
    short* dst[4] = {wall, wall + 256 * 512, wall + 512 * 512, wW};
    #pragma unroll
    for (int m = 0; m < 4; ++m) {
        float4 v = *(const float4*)(src[m] + (size_t)i * 4);
        short4 t = make_short4(f2bf(v.x), f2bf(v.y), f2bf(v.z), f2bf(v.w));
        *(short4*)(dst[m] + (size_t)i * 4) = t;
    }
    if (blockIdx.x == 0) {
        bcat[threadIdx.x] = thb[threadIdx.x];
        bcat[threadIdx.x + 256] = phb[threadIdx.x];
        bcat[threadIdx.x + 512] = gb[threadIdx.x];
    }
}

// ---------------------------------------------------------------------------
// NT bf16 MFMA GEMM: C(M,Nn) = A(M,K) @ B(Nn,K)^T, BMxBN tile, BK=32,
// 4 waves, 256 threads. Wave grid: NWC = BN/64 cols, NWR = 4/NWC rows;
// wave tile = (BM/NWR) x 64, MI = BM/NWR/16 row-fragments.
// ACVT: 0 none (A bf16, global_load_lds, 2-barrier loop);
//       1/2 A fp32/fp16 with fused softmax e=expf(v-m)*invZ -> fout + bf16
//       LDS, SOFTWARE-PIPELINED: double-buffered As/Bs, prefetched A regs,
//       counted-vmcnt barrier (B gloads stay in flight across it).
// EPI: 1 bf16 + col-bias; 2 bf16 + row-bias; 3 fp32 split-K partial;
//      4 fp32 + col-bias + ori^T add;
//      5 masked fp32 P store + per-(row,colblock) stats (max, expsum);
//      6 masked fp16 P store + stats (stats from the fp16-rounded values);
//      7 split output: cols<512 -> bf16 xcat (ld 512) + bias;
//                      cols>=512 -> transposed bf16 gxT (via stats ptr) + bias.
// EPI 5/6 use a bijective XCD-aware blockIdx swizzle (m204).
// ---------------------------------------------------------------------------
template <int EPI, int ACVT, int BM, int BN, int OCC = 2>
__global__ __launch_bounds__(256, OCC) void gemm_nt(
    const void* __restrict__ Avoid, const short* __restrict__ B,
    const float* __restrict__ bias, void* __restrict__ Cvoid,
    int M, int Nn, int K, int lda, int ldb, int nsplit,
    const float* __restrict__ ori,
    float* __restrict__ stats, const float* __restrict__ rowstat,
    float* __restrict__ fout)
{
    constexpr int NWC = BN / 64;
    constexpr int NWR = 4 / NWC;
    constexpr int MI  = BM / (NWR * 16);
    constexpr int NBUF = (ACVT != 0) ? 2 : 1;
    static_assert((EPI != 5 && EPI != 6 && EPI != 7) || NWC == 2, "stats/split epilogue assumes NWC==2");
    static_assert(ACVT == 0 || BN == 256, "pipelined vmcnt count assumes BN==256");
    __shared__ short As[NBUF * BM * 32];
    __shared__ short Bs[NBUF * BN * 32];
    const int tid = threadIdx.x;
    const int w = tid >> 6, lane = tid & 63;

    // XCD-aware bijective swizzle for the big P GEMM
    int bx = blockIdx.x, by = blockIdx.y;
    if constexpr (EPI == 5 || EPI == 6) {
        const int nwg = gridDim.x * gridDim.y;
        const int orig = by * gridDim.x + bx;
        const int q = nwg >> 3, r = nwg & 7;
        const int xcd = orig & 7, idx = orig >> 3;
        const int wg = (xcd < r ? xcd * (q + 1) : r * (q + 1) + (xcd - r) * q) + idx;
        bx = wg % gridDim.x; by = wg / gridDim.x;
    }
    const int m0 = by * BM, n0 = bx * BN;
    const int wr = w / NWC, wc = w % NWC;
    const int wrow = wr * (MI * 16);

    const int kper = K / 32 / nsplit;
    const int kt0 = blockIdx.z * kper, kt1 = kt0 + kper;

    f32x4 acc[MI][4] = {};

    const int sr = tid >> 2;          // 0..63
    const int sc = (tid & 3) * 8;     // k offset of 16B chunk
    const short* Ab = (const short*)Avoid;

    if constexpr (ACVT == 0) {
        for (int kt = kt0; kt < kt1; ++kt) {
            const int k0 = kt * 32;
            #pragma unroll
            for (int p = 0; p < BM / 64; ++p)
                gload16(Ab + (size_t)(m0 + p * 64 + sr) * lda + k0 + sc,
                        &As[(p * 64 + sr) * 32 + sc]);
            #pragma unroll
            for (int p = 0; p < BN / 64; ++p)
                gload16(B + (size_t)(n0 + p * 64 + sr) * ldb + k0 + sc,
                        &Bs[(p * 64 + sr) * 32 + sc]);
            __syncthreads();

            bf16x8 af[MI], bfr[4];
            #pragma unroll
            for (int i = 0; i < MI; ++i)
                af[i] = *(bf16x8*)&As[(wrow + i * 16 + (lane & 15)) * 32 + (lane >> 4) * 8];
            #pragma unroll
            for (int j = 0; j < 4; ++j)
                bfr[j] = *(bf16x8*)&Bs[(wc * 64 + j * 16 + (lane & 15)) * 32 + (lane >> 4) * 8];
            #pragma unroll
            for (int i = 0; i < MI; ++i)
                #pragma unroll
                for (int j = 0; j < 4; ++j)
                    acc[i][j] = __builtin_amdgcn_mfma_f32_16x16x32_bf16(af[i], bfr[j], acc[i][j], 0, 0, 0);
            __syncthreads();
        }
    } else {
        // -------- software-pipelined fused-softmax staging path --------
        constexpr int EPT = BM * 32 / 256;   // elems per thread
        static_assert(EPT == 4, "pipelined ACVT path assumes EPT==4");
        constexpr int TPR = 32 / EPT;        // threads per row
        const int a_r = tid / TPR;
        const int a_c = (tid % TPR) * EPT;
        float2 st = ((const float2*)rowstat)[m0 + a_r];
        const float rm = st.x, rz = st.y;
        using AV = typename avec_sel<ACVT>::t;
        const AV* Arow = (const AV*)((const char*)Avoid
                         + ((size_t)(m0 + a_r) * lda) * (ACVT == 2 ? 2 : 4));
        float* frow = fout + (size_t)(m0 + a_r) * lda;

        // prologue: A(kt0) regs + B(kt0) gloads
        AV hv = Arow[(kt0 * 32 + a_c) / 4];
        #pragma unroll
        for (int p = 0; p < BN / 64; ++p)
            gload16(B + (size_t)(n0 + p * 64 + sr) * ldb + kt0 * 32 + sc,
                    &Bs[(p * 64 + sr) * 32 + sc]);

        for (int kt = kt0; kt < kt1; ++kt) {
            const int cur = (kt - kt0) & 1;
            const int kc = kt * 32 + a_c;
            // process A(kt): exp, f_div_C store, bf16 -> As[cur]
            float4 vf;
            if constexpr (ACVT == 2) {
                vf.x = h2f(hv.x); vf.y = h2f(hv.y); vf.z = h2f(hv.z); vf.w = h2f(hv.w);
            } else {
                vf.x = hv.x; vf.y = hv.y; vf.z = hv.z; vf.w = hv.w;
            }
            float4 e;
            e.x = expf(vf.x - rm) * rz; e.y = expf(vf.y - rm) * rz;
            e.z = expf(vf.z - rm) * rz; e.w = expf(vf.w - rm) * rz;
            *(float4*)(frow + kc) = e;   // f_div_C output (exactly once)
            short4 t = make_short4(f2bf(e.x), f2bf(e.y), f2bf(e.z), f2bf(e.w));
            *(short4*)&As[cur * BM * 32 + a_r * 32 + a_c] = t;

            if (kt + 1 < kt1) {
                // prefetch A(kt+1) regs, then issue B(kt+1) -> other buffer
                hv = Arow[((kt + 1) * 32 + a_c) / 4];
                #pragma unroll
                for (int p = 0; p < BN / 64; ++p)
                    gload16(B + (size_t)(n0 + p * 64 + sr) * ldb + (kt + 1) * 32 + sc,
                            &Bs[(cur ^ 1) * BN * 32 + (p * 64 + sr) * 32 + sc]);
                // wait B(kt) only: 6 newer vmem ops (1 store + 1 load + 4 gloads)
                asm volatile("s_waitcnt vmcnt(6) lgkmcnt(0)\n\ts_barrier" ::: "memory");
            } else {
                // tail: only the f_div_C store is newer than B(kt)
                asm volatile("s_waitcnt vmcnt(1) lgkmcnt(0)\n\ts_barrier" ::: "memory");
            }

            bf16x8 af[MI], bfr[4];
            #pragma unroll
            for (int i = 0; i < MI; ++i)
                af[i] = *(bf16x8*)&As[cur * BM * 32 + (wrow + i * 16 + (lane & 15)) * 32 + (lane >> 4) * 8];
            #pragma unroll
            for (int j = 0; j < 4; ++j)
                bfr[j] = *(bf16x8*)&Bs[cur * BN * 32 + (wc * 64 + j * 16 + (lane & 15)) * 32 + (lane >> 4) * 8];
            #pragma unroll
            for (int i = 0; i < MI; ++i)
                #pragma unroll
                for (int j = 0; j < 4; ++j)
                    acc[i][j] = __builtin_amdgcn_mfma_f32_16x16x32_bf16(af[i], bfr[j], acc[i][j], 0, 0, 0);
            // protect Bs[cur^1]/As[cur^1] writes of fast waves vs slow readers
            asm volatile("s_barrier" ::: "memory");
        }
    }

    // epilogue: C/D layout col=lane&15, row=(lane>>4)*4+reg  [m89-verified]
    const int col = lane & 15, rowq = lane >> 4;

    if constexpr (EPI == 5 || EPI == 6) {
        // masked raw-P store + flash-style per-(row, colblock) stats
        __shared__ float sm[NWC][BM];
        __shared__ float ss[NWC][BM];
        int cbj[4];
        #pragma unroll
        for (int j = 0; j < 4; ++j)
            cbj[j] = (n0 + wc * 64 + j * 16 + col) / BLKSZ;
        #pragma unroll
        for (int i = 0; i < MI; ++i) {
            #pragma unroll
            for (int r = 0; r < 4; ++r) {
                const int trow = wrow + i * 16 + rowq * 4 + r;
                const int grow = m0 + trow;
                const int rb = grow / BLKSZ;
                float vj[4];
                float vmax = -1e30f;
                #pragma unroll
                for (int j = 0; j < 4; ++j) {
                    float v = acc[i][j][r];
                    if (cbj[j] == rb) v = -30000.0f;   // mask: exp underflows to 0
                    const size_t idx = (size_t)grow * Nn + (n0 + wc * 64 + j * 16 + col);
                    if constexpr (EPI == 6) {
                        unsigned short hh = f2h(v);
                        ((unsigned short*)Cvoid)[idx] = hh;
                        v = h2f(hh);       // stats from rounded value
                    } else {
                        ((float*)Cvoid)[idx] = v;
                    }
                    vj[j] = v;
                    vmax = fmaxf(vmax, v);
                }
                #pragma unroll
                for (int off = 1; off < 16; off <<= 1)
                    vmax = fmaxf(vmax, __shfl_xor(vmax, off));
                float s = 0.f;
                #pragma unroll
                for (int j = 0; j < 4; ++j) s += expf(vj[j] - vmax);
                #pragma unroll
                for (int off = 1; off < 16; off <<= 1)
                    s += __shfl_xor(s, off);
                if (col == 0) { sm[wc][trow] = vmax; ss[wc][trow] = s; }
            }
        }
        __syncthreads();
        if (tid < BM) {
            const float ma = sm[0][tid], mb = sm[1][tid];
            const float mx = fmaxf(ma, mb);
            const float S = ss[0][tid] * expf(ma - mx) + ss[1][tid] * expf(mb - mx);
            ((float2*)stats)[(size_t)bx * M + (m0 + tid)] = make_float2(mx, S);
        }
    } else if constexpr (EPI == 7) {
        if (n0 < 512) {
            // xcat bf16, ld 512, col-bias
            #pragma unroll
            for (int i = 0; i < MI; ++i)
                #pragma unroll
                for (int j = 0; j < 4; ++j)
                    #pragma unroll
                    for (int r = 0; r < 4; ++r) {
                        const int grow = m0 + wrow + i * 16 + rowq * 4 + r;
                        const int gcol = n0 + wc * 64 + j * 16 + col;
                        ((short*)Cvoid)[(size_t)grow * 512 + gcol] =
                            f2bf(acc[i][j][r] + bias[gcol]);
                    }
        } else {
            // transposed store into gxT (CI, T), col-bias
            short* gxTp = (short*)stats;
            #pragma unroll
            for (int i = 0; i < MI; ++i)
                #pragma unroll
                for (int j = 0; j < 4; ++j) {
                    const int grow0 = m0 + wrow + i * 16 + rowq * 4;
                    const int gcol = n0 + wc * 64 + j * 16 + col;
                    const float bv = bias[gcol];
                    short4 t = make_short4(
                        f2bf(acc[i][j][0] + bv), f2bf(acc[i][j][1] + bv),
                        f2bf(acc[i][j][2] + bv), f2bf(acc[i][j][3] + bv));
                    *(short4*)&gxTp[(size_t)(gcol - 512) * T_DIM + grow0] = t;
                }
        }
    } else {
        #pragma unroll
        for (int i = 0; i < MI; ++i) {
            #pragma unroll
            for (int j = 0; j < 4; ++j) {
                #pragma unroll
                for (int r = 0; r < 4; ++r) {
                    const int grow = m0 + wrow + i * 16 + rowq * 4 + r;
                    const int gcol = n0 + wc * 64 + j * 16 + col;
                    const float v = acc[i][j][r];
                    if (EPI == 1) {
                        ((short*)Cvoid)[(size_t)grow * Nn + gcol] = f2bf(v + bias[gcol]);
                    } else if (EPI == 2) {
                        ((short*)Cvoid)[(size_t)grow * Nn + gcol] = f2bf(v + bias[grow]);
                    } else if (EPI == 3) {
                        ((float*)Cvoid)[(size_t)blockIdx.z * M * Nn + (size_t)grow * Nn + gcol] = v;
                    } else {
                        const int nb = grow / BLKSZ, bb = grow - nb * BLKSZ;
                        ((float*)Cvoid)[(size_t)grow * Nn + gcol] =
                            v + bias[gcol] + ori[((size_t)nb * C_DIM + gcol) * BLKSZ + bb];
                    }
                }
            }
        }
    }
}

// ---------------------------------------------------------------------------
// Combine per-colblock stats (NCB x T float2: max, expsum) -> per-row
// (max, 1/Z) via online merge. 23 blocks x 256 threads, one row per thread.
// ---------------------------------------------------------------------------
__global__ __launch_bounds__(256) void combine_stats_kernel(
    const float* __restrict__ stats, float* __restrict__ rowstat)
{
    const int row = blockIdx.x * 256 + threadIdx.x;
    float m = -1e30f, Z = 0.f;
    for (int cb = 0; cb < NCB; ++cb) {
        float2 p = ((const float2*)stats)[(size_t)cb * T_DIM + row];
        float nm = fmaxf(m, p.x);
        Z = Z * expf(m - nm) + p.y * expf(p.x - nm);
        m = nm;
    }
    ((float2*)rowstat)[row] = make_float2(m, 1.0f / Z);
}

// ---------------------------------------------------------------------------
// Reduce split-K partials (ns, T, CI) fp32 -> y (T, CI) bf16.
// ---------------------------------------------------------------------------
__global__ __launch_bounds__(256) void reduce_y_kernel(
    const float* __restrict__ part, short* __restrict__ y, int ns)
{
    const size_t i = (size_t)blockIdx.x * 256 + threadIdx.x;  // float4 index
    float4 s = *(const float4*)(part + i * 4);
    for (int z = 1; z < ns; ++z) {
        float4 v = *(const float4*)(part + (size_t)z * T_DIM * CI + i * 4);
        s.x += v.x; s.y += v.y; s.z += v.z; s.w += v.w;
    }
    short4 t = make_short4(f2bf(s.x), f2bf(s.y), f2bf(s.z), f2bf(s.w));
    *(short4*)(y + i * 4) = t;
}

// ---------------------------------------------------------------------------
extern "C" void kernel_launch(void* const* d_in, const int* in_sizes, int n_in,
                              void* d_out, int out_size, void* d_ws, size_t ws_size,
                              hipStream_t stream)
{
    const float* ori     = (const float*)d_in[0];
    const float* gamma   = (const float*)d_in[1];
    const float* beta    = (const float*)d_in[2];
    const float* mean    = (const float*)d_in[3];
    const float* var     = (const float*)d_in[4];
    const float* theta_w = (const float*)d_in[5];
    const float* theta_b = (const float*)d_in[6];
    const float* phi_w   = (const float*)d_in[7];
    const float* phi_b   = (const float*)d_in[8];
    const float* g_w     = (const float*)d_in[9];
    const float* g_b     = (const float*)d_in[10];
    const float* W_w     = (const float*)d_in[11];
    const float* W_b     = (const float*)d_in[12];

    float* out = (float*)d_out;                    // att_fea (T, C), then f_div_C (T, T)
    float* P   = out + (size_t)T_DIM * C_DIM;      // f_div_C region

    char* wsb = (char*)d_ws;
    short* feat = (short*)wsb;  wsb += (size_t)T_DIM * C_DIM * 2;   // 6.03 MB
    short* xcat = (short*)wsb;  wsb += (size_t)T_DIM * 512 * 2;     // 6.03 MB (xth|xph)
    short* gxT  = (short*)wsb;  wsb += (size_t)CI * T_DIM * 2;      // 3.01 MB (CI, T)
    short* wall = (short*)wsb;  wsb += (size_t)768 * C_DIM * 2;     // 0.79 MB
    short* wW   = (short*)wsb;  wsb += (size_t)C_DIM * CI * 2;
    float* bcat = (float*)wsb;  wsb += 768 * 4;
    short* ybf  = (short*)wsb;  wsb += (size_t)T_DIM * CI * 2;      // 3.01 MB
    float* rowstat = (float*)wsb; wsb += (size_t)T_DIM * 8;         // 47 KB

    const size_t base   = (size_t)(wsb - (char*)d_ws);
    const size_t p16sz  = (size_t)T_DIM * T_DIM * 2;                // 69.3 MB
    const size_t ypsz4  = 4u * (size_t)T_DIM * CI * 4u;             // 24.1 MB
    const bool bigws = ws_size >= base + p16sz + ypsz4;

    // 1) BN + ReLU + transpose -> feat bf16; weights -> bf16 (+ packed bias)
    bn_relu_kernel<<<dim3(2, 128), 256, 0, stream>>>(ori, gamma, beta, mean, var, feat);
    cvt_kernel<<<128, 256, 0, stream>>>(theta_w, phi_w, g_w, W_w, theta_b, phi_b, g_b,
                                        wall, wW, bcat);

    // 2) merged: [xth | xph | gx] = feat @ wall^T + bcat  (M=T, Nn=768, K=512)
    //    cols<512 -> xcat bf16 (ld 512); cols>=512 -> gxT transposed (CI, T)
    gemm_nt<7, 0, 128, 128><<<dim3(6, T_DIM / 128), 256, 0, stream>>>(
        feat, wall, bcat, xcat, T_DIM, 768, C_DIM, C_DIM, C_DIM, 1, nullptr,
        (float*)gxT, nullptr, nullptr);

    if (bigws) {
        // --- fp16 raw-P path ---
        unsigned short* p16 = (unsigned short*)wsb;
        float* ypart = (float*)(wsb + p16sz);
        float* stats = ypart;   // 2.17 MB alias, consumed before ypart written

        // 3) P16 = mask(xth @ xph^T) fp16 + softmax stats (XCD-swizzled)
        gemm_nt<6, 0, 128, 128><<<dim3(T_DIM / 128, T_DIM / 128), 256, 0, stream>>>(
            xcat, xcat + CI, nullptr, p16, T_DIM, T_DIM, CI, 512, 512, 1, nullptr,
            stats, nullptr, nullptr);
        // 4) per-row (max, 1/Z)
        combine_stats_kernel<<<T_DIM / 256, 256, 0, stream>>>(stats, rowstat);
        // 5) ypart[z] = softmax(P16) @ gxT^T, pipelined fused-softmax staging,
        //    writes f_div_C fp32 to out region (each element staged once)
        gemm_nt<3, 2, 32, 256, 4><<<dim3(1, T_DIM / 32, 4), 256, 0, stream>>>(
            p16, gxT, nullptr, ypart, T_DIM, CI, T_DIM, T_DIM, T_DIM, 4, nullptr,
            nullptr, rowstat, P);
        reduce_y_kernel<<<(T_DIM * CI / 4) / 256, 256, 0, stream>>>(ypart, ybf, 4);
    } else {
        // --- fallback: fp32 raw P in out region, softmax in place ---
        float* ypart = (float*)wsb;
        float* stats = ypart;
        const int ns = (ws_size >= base + ypsz4) ? 4 : 2;

        gemm_nt<5, 0, 128, 128><<<dim3(T_DIM / 128, T_DIM / 128), 256, 0, stream>>>(
            xcat, xcat + CI, nullptr, P, T_DIM, T_DIM, CI, 512, 512, 1, nullptr,
            stats, nullptr, nullptr);
        combine_stats_kernel<<<T_DIM / 256, 256, 0, stream>>>(stats, rowstat);
        gemm_nt<3, 1, 32, 256, 4><<<dim3(1, T_DIM / 32, ns), 256, 0, stream>>>(
            P, gxT, nullptr, ypart, T_DIM, CI, T_DIM, T_DIM, T_DIM, ns, nullptr,
            nullptr, rowstat, P);
        reduce_y_kernel<<<(T_DIM * CI / 4) / 256, 256, 0, stream>>>(ypart, ybf, ns);
    }

    // 6) att_fea = y @ wW^T + W_b + ori^T  (M=T, Nn=C, K=CI), fp32 out
    gemm_nt<4, 0, 128, 128><<<dim3(C_DIM / 128, T_DIM / 128), 256, 0, stream>>>(
        ybf, wW, W_b, out, T_DIM, C_DIM, CI, CI, CI, 1, ori,
        nullptr, nullptr, nullptr);
}

// Round 4
// 331.157 us; speedup vs baseline: 1.1098x; 1.0284x over previous
//
#include <hip/hip_runtime.h>
#include <math.h>

#define N_BATCH 128
#define C_DIM   512
#define BLKSZ   46
#define T_DIM   (N_BATCH * BLKSZ)   // 5888
#define CI      256
#define EPS_BN  1e-5f
#define NCB     (T_DIM / 128)       // 46 col-blocks in the P GEMM

typedef __attribute__((ext_vector_type(8))) short bf16x8;
typedef __attribute__((ext_vector_type(4))) float f32x4;

__device__ __forceinline__ short f2bf(float f) {
    union { float f; unsigned u; } v; v.f = f;
    unsigned r = v.u + 0x7fffu + ((v.u >> 16) & 1u);
    return (short)(r >> 16);
}

__device__ __forceinline__ float h2f(unsigned short h) {
    _Float16 x; __builtin_memcpy(&x, &h, 2); return (float)x;
}
__device__ __forceinline__ unsigned short f2h(float f) {
    _Float16 x = (_Float16)f; unsigned short u; __builtin_memcpy(&u, &x, 2); return u;
}

__device__ __forceinline__ void gload16(const void* g, void* l) {
    __builtin_amdgcn_global_load_lds((__attribute__((address_space(1))) void*)g,
                                     (__attribute__((address_space(3))) void*)l,
                                     16, 0, 0);
}

template <int A> struct avec_sel { using t = float4; };
template <> struct avec_sel<2> { using t = ushort4; };

// ---------------------------------------------------------------------------
// BN(inference)+ReLU+transpose: ori (N,C,46) fp32 -> feat (T, C) bf16.
// ---------------------------------------------------------------------------
__global__ __launch_bounds__(256) void bn_relu_kernel(
    const float* __restrict__ ori, const float* __restrict__ gamma,
    const float* __restrict__ beta, const float* __restrict__ mean,
    const float* __restrict__ var, short* __restrict__ feat)
{
    __shared__ short tile[256 * BLKSZ];
    const int n = blockIdx.y;
    const int c0 = blockIdx.x * 256;
    const int tid = threadIdx.x;
    for (int i = tid; i < 256 * BLKSZ; i += 256) {
        int cl = i / BLKSZ, b = i - cl * BLKSZ;
        int c = c0 + cl;
        float inv = gamma[c] * rsqrtf(var[c] + EPS_BN);
        float v = ori[((size_t)n * C_DIM + c) * BLKSZ + b] * inv + (beta[c] - mean[c] * inv);
        tile[cl * BLKSZ + b] = f2bf(fmaxf(v, 0.0f));
    }
    __syncthreads();
    for (int i = tid; i < BLKSZ * 256; i += 256) {
        int b = i >> 8, cl = i & 255;
        feat[(size_t)(n * BLKSZ + b) * C_DIM + c0 + cl] = tile[cl * BLKSZ + b];
    }
}

// ---------------------------------------------------------------------------
// Convert weights fp32->bf16: theta_w+phi_w+g_w packed into wall (768 x 512),
// plus wW. Block 0 additionally packs bcat = [theta_b; phi_b; g_b] (fp32).
// ---------------------------------------------------------------------------
__global__ __launch_bounds__(256) void cvt_kernel(
    const float* __restrict__ thw, const float* __restrict__ phw,
    const float* __restrict__ gw, const float* __restrict__ Ww,
    const float* __restrict__ thb, const float* __restrict__ phb,
    const float* __restrict__ gb,
    short* __restrict__ wall, short* __restrict__ wW, float* __restrict__ bcat)
{
    const int i = blockIdx.x * 256 + threadIdx.x;  // float4 index, 32768 per mat
    const float* src[4] = {thw, phw, gw, Ww};
    short* dst[4] = {wall, wall + 256 * 512, wall + 512 * 512, wW};
    #pragma unroll
    for (int m = 0; m < 4; ++m) {
        float4 v = *(const float4*)(src[m] + (size_t)i * 4);
        short4 t = make_short4(f2bf(v.x), f2bf(v.y), f2bf(v.z), f2bf(v.w));
        *(short4*)(dst[m] + (size_t)i * 4) = t;
    }
    if (blockIdx.x == 0) {
        bcat[threadIdx.x] = thb[threadIdx.x];
        bcat[threadIdx.x + 256] = phb[threadIdx.x];
        bcat[threadIdx.x + 512] = gb[threadIdx.x];
    }
}

// ---------------------------------------------------------------------------
// NT bf16 MFMA GEMM: C(M,Nn) = A(M,K) @ B(Nn,K)^T, BMxBN tile, BK=32,
// 4 waves, 256 threads. Wave grid: NWC = BN/64 cols, NWR = 4/NWC rows;
// wave tile = (BM/NWR) x 64, MI = BM/NWR/16 row-fragments.
// ACVT: 0 none (A bf16): 2-deep global_load_lds pipeline, double-buffered
//       LDS, counted vmcnt(4) barriers (stage t+1 stays in flight over MFMA).
//       1/2 A fp32/fp16 with fused softmax e=expf(v-m)*invZ -> fout + bf16
//       LDS: 2-deep A-reg prefetch, triple-buffered B LDS, counted vmcnt(6).
// EPI: 1 bf16 + col-bias; 2 bf16 + row-bias; 3 fp16 split-K partial;
//      4 fp32 + col-bias + ori^T add;
//      5 masked fp32 P store + per-(row,colblock) stats (max, expsum);
//      6 masked fp16 P store + stats (stats from the fp16-rounded values);
//      7 split output: cols<512 -> bf16 xcat (ld 512) + bias;
//                      cols>=512 -> transposed bf16 gxT (via stats ptr) + bias.
// EPI 5/6 use a bijective XCD-aware blockIdx swizzle (m204).
// ---------------------------------------------------------------------------
template <int EPI, int ACVT, int BM, int BN, int OCC = 2>
__global__ __launch_bounds__(256, OCC) void gemm_nt(
    const void* __restrict__ Avoid, const short* __restrict__ B,
    const float* __restrict__ bias, void* __restrict__ Cvoid,
    int M, int Nn, int K, int lda, int ldb, int nsplit,
    const float* __restrict__ ori,
    float* __restrict__ stats, const float* __restrict__ rowstat,
    float* __restrict__ fout)
{
    constexpr int NWC = BN / 64;
    constexpr int NWR = 4 / NWC;
    constexpr int MI  = BM / (NWR * 16);
    constexpr int NBB = (ACVT != 0) ? 3 : 2;     // B LDS buffers
    static_assert((EPI != 5 && EPI != 6 && EPI != 7) || NWC == 2, "stats/split epilogue assumes NWC==2");
    static_assert(ACVT == 0 || (BN == 256 && BM == 32), "pipelined ACVT path geometry");
    static_assert(ACVT != 0 || (BM / 64 + BN / 64 == 4), "vmcnt(4) assumes 4 gloads/stage");
    __shared__ short As[2 * BM * 32];
    __shared__ short Bs[NBB * BN * 32];
    const int tid = threadIdx.x;
    const int w = tid >> 6, lane = tid & 63;

    // XCD-aware bijective swizzle for the big P GEMM
    int bx = blockIdx.x, by = blockIdx.y;
    if constexpr (EPI == 5 || EPI == 6) {
        const int nwg = gridDim.x * gridDim.y;
        const int orig = by * gridDim.x + bx;
        const int q = nwg >> 3, r = nwg & 7;
        const int xcd = orig & 7, idx = orig >> 3;
        const int wg = (xcd < r ? xcd * (q + 1) : r * (q + 1) + (xcd - r) * q) + idx;
        bx = wg % gridDim.x; by = wg / gridDim.x;
    }
    const int m0 = by * BM, n0 = bx * BN;
    const int wr = w / NWC, wc = w % NWC;
    const int wrow = wr * (MI * 16);

    const int kper = K / 32 / nsplit;
    const int kt0 = blockIdx.z * kper, kt1 = kt0 + kper;
    const int ktn = kt1 - kt0;

    f32x4 acc[MI][4] = {};

    const int sr = tid >> 2;          // 0..63
    const int sc = (tid & 3) * 8;     // k offset of 16B chunk
    const short* Ab = (const short*)Avoid;

    if constexpr (ACVT == 0) {
        auto stageAB = [&](int kt, int buf) {
            const int k0 = kt * 32;
            #pragma unroll
            for (int p = 0; p < BM / 64; ++p)
                gload16(Ab + (size_t)(m0 + p * 64 + sr) * lda + k0 + sc,
                        &As[buf * BM * 32 + (p * 64 + sr) * 32 + sc]);
            #pragma unroll
            for (int p = 0; p < BN / 64; ++p)
                gload16(B + (size_t)(n0 + p * 64 + sr) * ldb + k0 + sc,
                        &Bs[buf * BN * 32 + (p * 64 + sr) * 32 + sc]);
        };
        stageAB(kt0, 0);
        if (ktn > 1) stageAB(kt0 + 1, 1);
        if (ktn > 1) asm volatile("s_waitcnt vmcnt(4)\n\ts_barrier" ::: "memory");
        else         asm volatile("s_waitcnt vmcnt(0)\n\ts_barrier" ::: "memory");

        for (int t = 0; t < ktn; ++t) {
            const int cur = t & 1;
            bf16x8 af[MI], bfr[4];
            #pragma unroll
            for (int i = 0; i < MI; ++i)
                af[i] = *(bf16x8*)&As[cur * BM * 32 + (wrow + i * 16 + (lane & 15)) * 32 + (lane >> 4) * 8];
            #pragma unroll
            for (int j = 0; j < 4; ++j)
                bfr[j] = *(bf16x8*)&Bs[cur * BN * 32 + (wc * 64 + j * 16 + (lane & 15)) * 32 + (lane >> 4) * 8];
            // all waves' reads of buf[cur] complete -> safe to restage it
            asm volatile("s_waitcnt lgkmcnt(0)\n\ts_barrier" ::: "memory");
            if (t + 2 < ktn) stageAB(kt0 + t + 2, cur);
            #pragma unroll
            for (int i = 0; i < MI; ++i)
                #pragma unroll
                for (int j = 0; j < 4; ++j)
                    acc[i][j] = __builtin_amdgcn_mfma_f32_16x16x32_bf16(af[i], bfr[j], acc[i][j], 0, 0, 0);
            if (t + 2 < ktn)      asm volatile("s_waitcnt vmcnt(4)\n\ts_barrier" ::: "memory");
            else if (t + 1 < ktn) asm volatile("s_waitcnt vmcnt(0)\n\ts_barrier" ::: "memory");
            // last iteration: no further LDS reuse, fall through to epilogue
        }
    } else {
        // -------- 2-deep pipelined fused-softmax staging path --------
        constexpr int EPT = BM * 32 / 256;   // elems per thread (=4)
        static_assert(EPT == 4, "pipelined ACVT path assumes EPT==4");
        constexpr int TPR = 32 / EPT;        // threads per row
        const int a_r = tid / TPR;
        const int a_c = (tid % TPR) * EPT;
        float2 st = ((const float2*)rowstat)[m0 + a_r];
        const float rm = st.x, rz = st.y;
        using AV = typename avec_sel<ACVT>::t;
        const AV* Arow = (const AV*)((const char*)Avoid
                         + ((size_t)(m0 + a_r) * lda) * (ACVT == 2 ? 2 : 4));
        float* frow = fout + (size_t)(m0 + a_r) * lda;

        auto stageB = [&](int kt, int buf) {
            #pragma unroll
            for (int p = 0; p < BN / 64; ++p)
                gload16(B + (size_t)(n0 + p * 64 + sr) * ldb + kt * 32 + sc,
                        &Bs[buf * BN * 32 + (p * 64 + sr) * 32 + sc]);
        };

        // prologue: A(kt0), A(kt0+1) regs; B(kt0)->buf0, B(kt0+1)->buf1
        AV hva = Arow[(kt0 * 32 + a_c) / 4];
        AV hvb = hva;
        stageB(kt0, 0);
        if (ktn > 1) { hvb = Arow[((kt0 + 1) * 32 + a_c) / 4]; stageB(kt0 + 1, 1); }
        if (ktn > 1) asm volatile("s_waitcnt vmcnt(4)" ::: "memory");
        else         asm volatile("s_waitcnt vmcnt(0)" ::: "memory");

        int curB = 0, stB = 2;   // t%3 and (t+2)%3
        for (int t = 0; t < ktn; ++t) {
            const int kt = kt0 + t;
            const int curA = t & 1;
            // process A(t): exp, f_div_C store, bf16 -> As[curA]
            AV v = hva; hva = hvb;
            float4 vf;
            if constexpr (ACVT == 2) {
                vf.x = h2f(v.x); vf.y = h2f(v.y); vf.z = h2f(v.z); vf.w = h2f(v.w);
            } else {
                vf.x = v.x; vf.y = v.y; vf.z = v.z; vf.w = v.w;
            }
            float4 e;
            e.x = expf(vf.x - rm) * rz; e.y = expf(vf.y - rm) * rz;
            e.z = expf(vf.z - rm) * rz; e.w = expf(vf.w - rm) * rz;
            *(float4*)(frow + kt * 32 + a_c) = e;   // f_div_C output (exactly once)
            short4 tq = make_short4(f2bf(e.x), f2bf(e.y), f2bf(e.z), f2bf(e.w));
            *(short4*)&As[curA * BM * 32 + a_r * 32 + a_c] = tq;
            if (t + 2 < ktn) hvb = Arow[((kt + 2) * 32 + a_c) / 4];   // 2-deep A prefetch

            // As[curA] visible to all waves; B(t) landed (prev iter's vmcnt)
            asm volatile("s_waitcnt lgkmcnt(0)\n\ts_barrier" ::: "memory");
            if (t + 2 < ktn) stageB(kt + 2, stB);

            bf16x8 af[MI], bfr[4];
            #pragma unroll
            for (int i = 0; i < MI; ++i)
                af[i] = *(bf16x8*)&As[curA * BM * 32 + (wrow + i * 16 + (lane & 15)) * 32 + (lane >> 4) * 8];
            #pragma unroll
            for (int j = 0; j < 4; ++j)
                bfr[j] = *(bf16x8*)&Bs[curB * BN * 32 + (wc * 64 + j * 16 + (lane & 15)) * 32 + (lane >> 4) * 8];
            #pragma unroll
            for (int i = 0; i < MI; ++i)
                #pragma unroll
                for (int j = 0; j < 4; ++j)
                    acc[i][j] = __builtin_amdgcn_mfma_f32_16x16x32_bf16(af[i], bfr[j], acc[i][j], 0, 0, 0);

            // drain B(t+1) only: newest-6 = {store(t), A(t+2), B(t+2)x4} stay in flight
            if (t + 2 < ktn)      asm volatile("s_waitcnt vmcnt(6)\n\ts_barrier" ::: "memory");
            else if (t + 1 < ktn) asm volatile("s_waitcnt vmcnt(1)\n\ts_barrier" ::: "memory");
            else                  asm volatile("s_waitcnt vmcnt(0)\n\ts_barrier" ::: "memory");
            curB = (curB == 2) ? 0 : curB + 1;
            stB  = (stB == 2) ? 0 : stB + 1;
        }
    }

    // epilogue: C/D layout col=lane&15, row=(lane>>4)*4+reg  [m89-verified]
    const int col = lane & 15, rowq = lane >> 4;

    if constexpr (EPI == 5 || EPI == 6) {
        // masked raw-P store + flash-style per-(row, colblock) stats
        __shared__ float sm[NWC][BM];
        __shared__ float ss[NWC][BM];
        int cbj[4];
        #pragma unroll
        for (int j = 0; j < 4; ++j)
            cbj[j] = (n0 + wc * 64 + j * 16 + col) / BLKSZ;
        #pragma unroll
        for (int i = 0; i < MI; ++i) {
            #pragma unroll
            for (int r = 0; r < 4; ++r) {
                const int trow = wrow + i * 16 + rowq * 4 + r;
                const int grow = m0 + trow;
                const int rb = grow / BLKSZ;
                float vj[4];
                float vmax = -1e30f;
                #pragma unroll
                for (int j = 0; j < 4; ++j) {
                    float v = acc[i][j][r];
                    if (cbj[j] == rb) v = -30000.0f;   // mask: exp underflows to 0
                    const size_t idx = (size_t)grow * Nn + (n0 + wc * 64 + j * 16 + col);
                    if constexpr (EPI == 6) {
                        unsigned short hh = f2h(v);
                        ((unsigned short*)Cvoid)[idx] = hh;
                        v = h2f(hh);       // stats from rounded value
                    } else {
                        ((float*)Cvoid)[idx] = v;
                    }
                    vj[j] = v;
                    vmax = fmaxf(vmax, v);
                }
                #pragma unroll
                for (int off = 1; off < 16; off <<= 1)
                    vmax = fmaxf(vmax, __shfl_xor(vmax, off));
                float s = 0.f;
                #pragma unroll
                for (int j = 0; j < 4; ++j) s += expf(vj[j] - vmax);
                #pragma unroll
                for (int off = 1; off < 16; off <<= 1)
                    s += __shfl_xor(s, off);
                if (col == 0) { sm[wc][trow] = vmax; ss[wc][trow] = s; }
            }
        }
        __syncthreads();
        if (tid < BM) {
            const float ma = sm[0][tid], mb = sm[1][tid];
            const float mx = fmaxf(ma, mb);
            const float S = ss[0][tid] * expf(ma - mx) + ss[1][tid] * expf(mb - mx);
            ((float2*)stats)[(size_t)bx * M + (m0 + tid)] = make_float2(mx, S);
        }
    } else if constexpr (EPI == 7) {
        if (n0 < 512) {
            // xcat bf16, ld 512, col-bias
            #pragma unroll
            for (int i = 0; i < MI; ++i)
                #pragma unroll
                for (int j = 0; j < 4; ++j)
                    #pragma unroll
                    for (int r = 0; r < 4; ++r) {
                        const int grow = m0 + wrow + i * 16 + rowq * 4 + r;
                        const int gcol = n0 + wc * 64 + j * 16 + col;
                        ((short*)Cvoid)[(size_t)grow * 512 + gcol] =
                            f2bf(acc[i][j][r] + bias[gcol]);
                    }
        } else {
            // transposed store into gxT (CI, T), col-bias
            short* gxTp = (short*)stats;
            #pragma unroll
            for (int i = 0; i < MI; ++i)
                #pragma unroll
                for (int j = 0; j < 4; ++j) {
                    const int grow0 = m0 + wrow + i * 16 + rowq * 4;
                    const int gcol = n0 + wc * 64 + j * 16 + col;
                    const float bv = bias[gcol];
                    short4 t = make_short4(
                        f2bf(acc[i][j][0] + bv), f2bf(acc[i][j][1] + bv),
                        f2bf(acc[i][j][2] + bv), f2bf(acc[i][j][3] + bv));
                    *(short4*)&gxTp[(size_t)(gcol - 512) * T_DIM + grow0] = t;
                }
        }
    } else {
        #pragma unroll
        for (int i = 0; i < MI; ++i) {
            #pragma unroll
            for (int j = 0; j < 4; ++j) {
                #pragma unroll
                for (int r = 0; r < 4; ++r) {
                    const int grow = m0 + wrow + i * 16 + rowq * 4 + r;
                    const int gcol = n0 + wc * 64 + j * 16 + col;
                    const float v = acc[i][j][r];
                    if (EPI == 1) {
                        ((short*)Cvoid)[(size_t)grow * Nn + gcol] = f2bf(v + bias[gcol]);
                    } else if (EPI == 2) {
                        ((short*)Cvoid)[(size_t)grow * Nn + gcol] = f2bf(v + bias[grow]);
                    } else if (EPI == 3) {
                        ((unsigned short*)Cvoid)[(size_t)blockIdx.z * M * Nn + (size_t)grow * Nn + gcol] = f2h(v);
                    } else {
                        const int nb = grow / BLKSZ, bb = grow - nb * BLKSZ;
                        ((float*)Cvoid)[(size_t)grow * Nn + gcol] =
                            v + bias[gcol] + ori[((size_t)nb * C_DIM + gcol) * BLKSZ + bb];
                    }
                }
            }
        }
    }
}

// ---------------------------------------------------------------------------
// Combine per-colblock stats (NCB x T float2: max, expsum) -> per-row
// (max, 1/Z) via online merge. 23 blocks x 256 threads, one row per thread.
// ---------------------------------------------------------------------------
__global__ __launch_bounds__(256) void combine_stats_kernel(
    const float* __restrict__ stats, float* __restrict__ rowstat)
{
    const int row = blockIdx.x * 256 + threadIdx.x;
    float m = -1e30f, Z = 0.f;
    for (int cb = 0; cb < NCB; ++cb) {
        float2 p = ((const float2*)stats)[(size_t)cb * T_DIM + row];
        float nm = fmaxf(m, p.x);
        Z = Z * expf(m - nm) + p.y * expf(p.x - nm);
        m = nm;
    }
    ((float2*)rowstat)[row] = make_float2(m, 1.0f / Z);
}

// ---------------------------------------------------------------------------
// Reduce split-K partials (ns, T, CI) fp16 -> y (T, CI) bf16.
// ---------------------------------------------------------------------------
__global__ __launch_bounds__(256) void reduce_y_kernel(
    const unsigned short* __restrict__ part, short* __restrict__ y, int ns)
{
    const size_t i = (size_t)blockIdx.x * 256 + threadIdx.x;  // ushort4 index
    float s0 = 0.f, s1 = 0.f, s2 = 0.f, s3 = 0.f;
    for (int z = 0; z < ns; ++z) {
        ushort4 v = *(const ushort4*)(part + (size_t)z * T_DIM * CI + i * 4);
        s0 += h2f(v.x); s1 += h2f(v.y); s2 += h2f(v.z); s3 += h2f(v.w);
    }
    short4 t = make_short4(f2bf(s0), f2bf(s1), f2bf(s2), f2bf(s3));
    *(short4*)(y + i * 4) = t;
}

// ---------------------------------------------------------------------------
extern "C" void kernel_launch(void* const* d_in, const int* in_sizes, int n_in,
                              void* d_out, int out_size, void* d_ws, size_t ws_size,
                              hipStream_t stream)
{
    const float* ori     = (const float*)d_in[0];
    const float* gamma   = (const float*)d_in[1];
    const float* beta    = (const float*)d_in[2];
    const float* mean    = (const float*)d_in[3];
    const float* var     = (const float*)d_in[4];
    const float* theta_w = (const float*)d_in[5];
    const float* theta_b = (const float*)d_in[6];
    const float* phi_w   = (const float*)d_in[7];
    const float* phi_b   = (const float*)d_in[8];
    const float* g_w     = (const float*)d_in[9];
    const float* g_b     = (const float*)d_in[10];
    const float* W_w     = (const float*)d_in[11];
    const float* W_b     = (const float*)d_in[12];

    float* out = (float*)d_out;                    // att_fea (T, C), then f_div_C (T, T)
    float* P   = out + (size_t)T_DIM * C_DIM;      // f_div_C region

    char* wsb = (char*)d_ws;
    short* feat = (short*)wsb;  wsb += (size_t)T_DIM * C_DIM * 2;   // 6.03 MB
    short* xcat = (short*)wsb;  wsb += (size_t)T_DIM * 512 * 2;     // 6.03 MB (xth|xph)
    short* gxT  = (short*)wsb;  wsb += (size_t)CI * T_DIM * 2;      // 3.01 MB (CI, T)
    short* wall = (short*)wsb;  wsb += (size_t)768 * C_DIM * 2;     // 0.79 MB
    short* wW   = (short*)wsb;  wsb += (size_t)C_DIM * CI * 2;
    float* bcat = (float*)wsb;  wsb += 768 * 4;
    short* ybf  = (short*)wsb;  wsb += (size_t)T_DIM * CI * 2;      // 3.01 MB
    float* rowstat = (float*)wsb; wsb += (size_t)T_DIM * 8;         // 47 KB

    const size_t base   = (size_t)(wsb - (char*)d_ws);
    const size_t p16sz  = (size_t)T_DIM * T_DIM * 2;                // 69.3 MB
    const size_t ypsz4  = 4u * (size_t)T_DIM * CI * 2u;             // 12.1 MB (fp16)
    const bool bigws = ws_size >= base + p16sz + ypsz4;

    // 1) BN + ReLU + transpose -> feat bf16; weights -> bf16 (+ packed bias)
    bn_relu_kernel<<<dim3(2, 128), 256, 0, stream>>>(ori, gamma, beta, mean, var, feat);
    cvt_kernel<<<128, 256, 0, stream>>>(theta_w, phi_w, g_w, W_w, theta_b, phi_b, g_b,
                                        wall, wW, bcat);

    // 2) merged: [xth | xph | gx] = feat @ wall^T + bcat  (M=T, Nn=768, K=512)
    //    cols<512 -> xcat bf16 (ld 512); cols>=512 -> gxT transposed (CI, T)
    gemm_nt<7, 0, 128, 128><<<dim3(6, T_DIM / 128), 256, 0, stream>>>(
        feat, wall, bcat, xcat, T_DIM, 768, C_DIM, C_DIM, C_DIM, 1, nullptr,
        (float*)gxT, nullptr, nullptr);

    if (bigws) {
        // --- fp16 raw-P path ---
        unsigned short* p16 = (unsigned short*)wsb;
        unsigned short* ypart = (unsigned short*)(wsb + p16sz);
        float* stats = (float*)ypart;   // 2.17 MB alias, consumed before ypart written

        // 3) P16 = mask(xth @ xph^T) fp16 + softmax stats (XCD-swizzled)
        gemm_nt<6, 0, 128, 128><<<dim3(T_DIM / 128, T_DIM / 128), 256, 0, stream>>>(
            xcat, xcat + CI, nullptr, p16, T_DIM, T_DIM, CI, 512, 512, 1, nullptr,
            stats, nullptr, nullptr);
        // 4) per-row (max, 1/Z)
        combine_stats_kernel<<<T_DIM / 256, 256, 0, stream>>>(stats, rowstat);
        // 5) ypart[z] = softmax(P16) @ gxT^T, 2-deep pipelined fused-softmax
        //    staging, writes f_div_C fp32 to out region (each element once)
        gemm_nt<3, 2, 32, 256, 3><<<dim3(1, T_DIM / 32, 4), 256, 0, stream>>>(
            p16, gxT, nullptr, ypart, T_DIM, CI, T_DIM, T_DIM, T_DIM, 4, nullptr,
            nullptr, rowstat, P);
        reduce_y_kernel<<<(T_DIM * CI / 4) / 256, 256, 0, stream>>>(ypart, ybf, 4);
    } else {
        // --- fallback: fp32 raw P in out region, softmax in place ---
        unsigned short* ypart = (unsigned short*)wsb;
        float* stats = (float*)wsb;
        const int ns = (ws_size >= base + ypsz4) ? 4 : 2;

        gemm_nt<5, 0, 128, 128><<<dim3(T_DIM / 128, T_DIM / 128), 256, 0, stream>>>(
            xcat, xcat + CI, nullptr, P, T_DIM, T_DIM, CI, 512, 512, 1, nullptr,
            stats, nullptr, nullptr);
        combine_stats_kernel<<<T_DIM / 256, 256, 0, stream>>>(stats, rowstat);
        gemm_nt<3, 1, 32, 256, 3><<<dim3(1, T_DIM / 32, ns), 256, 0, stream>>>(
            P, gxT, nullptr, ypart, T_DIM, CI, T_DIM, T_DIM, T_DIM, ns, nullptr,
            nullptr, rowstat, P);
        reduce_y_kernel<<<(T_DIM * CI / 4) / 256, 256, 0, stream>>>(ypart, ybf, ns);
    }

    // 6) att_fea = y @ wW^T + W_b + ori^T  (M=T, Nn=C, K=CI), fp32 out
    gemm_nt<4, 0, 128, 128><<<dim3(C_DIM / 128, T_DIM / 128), 256, 0, stream>>>(
        ybf, wW, W_b, out, T_DIM, C_DIM, CI, CI, CI, 1, ori,
        nullptr, nullptr, nullptr);
}

// Round 5
// 330.762 us; speedup vs baseline: 1.1111x; 1.0012x over previous
//
#include <hip/hip_runtime.h>
#include <math.h>

#define N_BATCH 128
#define C_DIM   512
#define BLKSZ   46
#define T_DIM   (N_BATCH * BLKSZ)   // 5888
#define CI      256
#define EPS_BN  1e-5f
#define NCB     (T_DIM / 128)       // 46 col-blocks in the P GEMM

typedef __attribute__((ext_vector_type(8))) short bf16x8;
typedef __attribute__((ext_vector_type(4))) float f32x4;

__device__ __forceinline__ short f2bf(float f) {
    union { float f; unsigned u; } v; v.f = f;
    unsigned r = v.u + 0x7fffu + ((v.u >> 16) & 1u);
    return (short)(r >> 16);
}

__device__ __forceinline__ float h2f(unsigned short h) {
    _Float16 x; __builtin_memcpy(&x, &h, 2); return (float)x;
}
__device__ __forceinline__ unsigned short f2h(float f) {
    _Float16 x = (_Float16)f; unsigned short u; __builtin_memcpy(&u, &x, 2); return u;
}

__device__ __forceinline__ void gload16(const void* g, void* l) {
    __builtin_amdgcn_global_load_lds((__attribute__((address_space(1))) void*)g,
                                     (__attribute__((address_space(3))) void*)l,
                                     16, 0, 0);
}

template <int V> __device__ __forceinline__ void wait_vm_bar() {
    if constexpr (V == 0) asm volatile("s_waitcnt vmcnt(0)\n\ts_barrier" ::: "memory");
    else if constexpr (V == 1) asm volatile("s_waitcnt vmcnt(1)\n\ts_barrier" ::: "memory");
    else if constexpr (V == 2) asm volatile("s_waitcnt vmcnt(2)\n\ts_barrier" ::: "memory");
    else if constexpr (V == 3) asm volatile("s_waitcnt vmcnt(3)\n\ts_barrier" ::: "memory");
    else if constexpr (V == 4) asm volatile("s_waitcnt vmcnt(4)\n\ts_barrier" ::: "memory");
    else if constexpr (V == 6) asm volatile("s_waitcnt vmcnt(6)\n\ts_barrier" ::: "memory");
    else asm volatile("s_waitcnt vmcnt(8)\n\ts_barrier" ::: "memory");
}

template <int A> struct avec_sel { using t = float4; };
template <> struct avec_sel<2> { using t = ushort4; };

// ---------------------------------------------------------------------------
// Fused prep: blocks [0,256): BN+ReLU+transpose ori -> feat bf16;
// blocks [256,384): weights fp32->bf16 (wall = [theta;phi;g], wW) + bcat.
// ---------------------------------------------------------------------------
__global__ __launch_bounds__(256) void prep_kernel(
    const float* __restrict__ ori, const float* __restrict__ gamma,
    const float* __restrict__ beta, const float* __restrict__ mean,
    const float* __restrict__ var, short* __restrict__ feat,
    const float* __restrict__ thw, const float* __restrict__ phw,
    const float* __restrict__ gw, const float* __restrict__ Ww,
    const float* __restrict__ thb, const float* __restrict__ phb,
    const float* __restrict__ gb,
    short* __restrict__ wall, short* __restrict__ wW, float* __restrict__ bcat)
{
    __shared__ short tile[256 * BLKSZ];
    const int tid = threadIdx.x;
    if (blockIdx.x < 256) {
        const int n = blockIdx.x >> 1;
        const int c0 = (blockIdx.x & 1) * 256;
        for (int i = tid; i < 256 * BLKSZ; i += 256) {
            int cl = i / BLKSZ, b = i - cl * BLKSZ;
            int c = c0 + cl;
            float inv = gamma[c] * rsqrtf(var[c] + EPS_BN);
            float v = ori[((size_t)n * C_DIM + c) * BLKSZ + b] * inv + (beta[c] - mean[c] * inv);
            tile[cl * BLKSZ + b] = f2bf(fmaxf(v, 0.0f));
        }
        __syncthreads();
        for (int i = tid; i < BLKSZ * 256; i += 256) {
            int b = i >> 8, cl = i & 255;
            feat[(size_t)(n * BLKSZ + b) * C_DIM + c0 + cl] = tile[cl * BLKSZ + b];
        }
    } else {
        const int bx2 = blockIdx.x - 256;
        const int i = bx2 * 256 + tid;  // float4 index, 32768 per matrix
        const float* src[4] = {thw, phw, gw, Ww};
        short* dst[4] = {wall, wall + 256 * 512, wall + 512 * 512, wW};
        #pragma unroll
        for (int m = 0; m < 4; ++m) {
            float4 v = *(const float4*)(src[m] + (size_t)i * 4);
            short4 t = make_short4(f2bf(v.x), f2bf(v.y), f2bf(v.z), f2bf(v.w));
            *(short4*)(dst[m] + (size_t)i * 4) = t;
        }
        if (bx2 == 0) {
            bcat[tid] = thb[tid];
            bcat[tid + 256] = phb[tid];
            bcat[tid + 512] = gb[tid];
        }
    }
}

// ---------------------------------------------------------------------------
// NT bf16 MFMA GEMM: C(M,Nn) = A(M,K) @ B(Nn,K)^T, BMxBN tile, BK=32,
// 4 waves, 256 threads. Wave grid: NWC = BN/64 cols, NWR = 4/NWC rows;
// wave tile = (BM/NWR) x 64, MI = BM/NWR/16 row-fragments.
// ACVT: 0 none (A bf16): 2-deep global_load_lds pipeline, double-buffered
//       LDS, counted vmcnt(GL) barriers, GL = BM/64 + BN/64.
//       1/2 A fp32/fp16 with fused softmax e=expf(v-m)*invZ -> fout + bf16
//       LDS: per-block stats merge (replaces combine_stats kernel), 2-deep
//       A-reg prefetch, triple-buffered B LDS, counted vmcnt(6).
// EPI: 1 bf16 + col-bias; 2 bf16 + row-bias; 3 fp16 split-K partial;
//      4 fp32 + col-bias + ori^T add;
//      5 masked fp32 P store + per-(row,colblock) stats (max, expsum);
//      6 masked fp16 P store + stats (stats from the fp16-rounded values);
//      7 split output: cols<512 -> bf16 xcat (ld 512) + bias;
//                      cols>=512 -> transposed bf16 gxT (via stats ptr) + bias.
// EPI 5/6 use a bijective XCD-aware blockIdx swizzle (m204).
// ---------------------------------------------------------------------------
template <int EPI, int ACVT, int BM, int BN, int OCC = 2>
__global__ __launch_bounds__(256, OCC) void gemm_nt(
    const void* __restrict__ Avoid, const short* __restrict__ B,
    const float* __restrict__ bias, void* __restrict__ Cvoid,
    int M, int Nn, int K, int lda, int ldb, int nsplit,
    const float* __restrict__ ori,
    float* __restrict__ stats, const float* __restrict__ rowstat,
    float* __restrict__ fout)
{
    constexpr int NWC = BN / 64;
    constexpr int NWR = 4 / NWC;
    constexpr int MI  = BM / (NWR * 16);
    constexpr int NBB = (ACVT != 0) ? 3 : 2;     // B LDS buffers
    constexpr int GL  = BM / 64 + BN / 64;       // gloads per stage (ACVT==0)
    static_assert((EPI != 5 && EPI != 6 && EPI != 7) || NWC == 2, "stats/split epilogue assumes NWC==2");
    static_assert(ACVT == 0 || (BN == 256 && BM == 32), "pipelined ACVT path geometry");
    __shared__ short As[2 * BM * 32];
    __shared__ short Bs[NBB * BN * 32];
    const int tid = threadIdx.x;
    const int w = tid >> 6, lane = tid & 63;

    // XCD-aware bijective swizzle for the big P GEMM
    int bx = blockIdx.x, by = blockIdx.y;
    if constexpr (EPI == 5 || EPI == 6) {
        const int nwg = gridDim.x * gridDim.y;
        const int orig = by * gridDim.x + bx;
        const int q = nwg >> 3, r = nwg & 7;
        const int xcd = orig & 7, idx = orig >> 3;
        const int wg = (xcd < r ? xcd * (q + 1) : r * (q + 1) + (xcd - r) * q) + idx;
        bx = wg % gridDim.x; by = wg / gridDim.x;
    }
    const int m0 = by * BM, n0 = bx * BN;
    const int wr = w / NWC, wc = w % NWC;
    const int wrow = wr * (MI * 16);

    const int kper = K / 32 / nsplit;
    const int kt0 = blockIdx.z * kper, kt1 = kt0 + kper;
    const int ktn = kt1 - kt0;

    f32x4 acc[MI][4] = {};

    const int sr = tid >> 2;          // 0..63
    const int sc = (tid & 3) * 8;     // k offset of 16B chunk
    const short* Ab = (const short*)Avoid;

    if constexpr (ACVT == 0) {
        auto stageAB = [&](int kt, int buf) {
            const int k0 = kt * 32;
            #pragma unroll
            for (int p = 0; p < BM / 64; ++p)
                gload16(Ab + (size_t)(m0 + p * 64 + sr) * lda + k0 + sc,
                        &As[buf * BM * 32 + (p * 64 + sr) * 32 + sc]);
            #pragma unroll
            for (int p = 0; p < BN / 64; ++p)
                gload16(B + (size_t)(n0 + p * 64 + sr) * ldb + k0 + sc,
                        &Bs[buf * BN * 32 + (p * 64 + sr) * 32 + sc]);
        };
        stageAB(kt0, 0);
        if (ktn > 1) stageAB(kt0 + 1, 1);
        if (ktn > 1) wait_vm_bar<GL>();
        else         wait_vm_bar<0>();

        for (int t = 0; t < ktn; ++t) {
            const int cur = t & 1;
            bf16x8 af[MI], bfr[4];
            #pragma unroll
            for (int i = 0; i < MI; ++i)
                af[i] = *(bf16x8*)&As[cur * BM * 32 + (wrow + i * 16 + (lane & 15)) * 32 + (lane >> 4) * 8];
            #pragma unroll
            for (int j = 0; j < 4; ++j)
                bfr[j] = *(bf16x8*)&Bs[cur * BN * 32 + (wc * 64 + j * 16 + (lane & 15)) * 32 + (lane >> 4) * 8];
            // all waves' reads of buf[cur] complete -> safe to restage it
            asm volatile("s_waitcnt lgkmcnt(0)\n\ts_barrier" ::: "memory");
            if (t + 2 < ktn) stageAB(kt0 + t + 2, cur);
            __builtin_amdgcn_s_setprio(1);
            #pragma unroll
            for (int i = 0; i < MI; ++i)
                #pragma unroll
                for (int j = 0; j < 4; ++j)
                    acc[i][j] = __builtin_amdgcn_mfma_f32_16x16x32_bf16(af[i], bfr[j], acc[i][j], 0, 0, 0);
            __builtin_amdgcn_s_setprio(0);
            if (t + 2 < ktn)      wait_vm_bar<GL>();
            else if (t + 1 < ktn) wait_vm_bar<0>();
            // last iteration: no further LDS reuse, fall through to epilogue
        }
    } else {
        // -------- 2-deep pipelined fused-softmax staging path --------
        constexpr int EPT = BM * 32 / 256;   // elems per thread (=4)
        static_assert(EPT == 4, "pipelined ACVT path assumes EPT==4");
        constexpr int TPR = 32 / EPT;        // threads per row
        const int a_r = tid / TPR;
        const int a_c = (tid % TPR) * EPT;

        // per-block softmax-stat merge (replaces combine_stats kernel);
        // uses As as fp32 scratch BEFORE any staging touches it.
        float rm, rz;
        {
            float2* scr = (float2*)As;           // 512 float2 capacity
            const int rr = tid >> 3, cc = tid & 7;   // 32 rows x 8 chunks
            float mm = -1e30f, ZZ = 0.f;
            for (int cb = cc; cb < NCB; cb += 8) {
                float2 p = ((const float2*)stats)[(size_t)cb * M + (m0 + rr)];
                float nm = fmaxf(mm, p.x);
                ZZ = ZZ * expf(mm - nm) + p.y * expf(p.x - nm);
                mm = nm;
            }
            scr[rr * 8 + cc] = make_float2(mm, ZZ);
            __syncthreads();
            if (tid < BM) {
                float m2 = -1e30f, Z2 = 0.f;
                #pragma unroll
                for (int c = 0; c < 8; ++c) {
                    float2 p = scr[tid * 8 + c];
                    float nm = fmaxf(m2, p.x);
                    Z2 = Z2 * expf(m2 - nm) + p.y * expf(p.x - nm);
                    m2 = nm;
                }
                scr[256 + tid] = make_float2(m2, 1.0f / Z2);
            }
            __syncthreads();
            float2 st = scr[256 + a_r];
            rm = st.x; rz = st.y;
            __syncthreads();   // all reads done before staging overwrites As
        }

        using AV = typename avec_sel<ACVT>::t;
        const AV* Arow = (const AV*)((const char*)Avoid
                         + ((size_t)(m0 + a_r) * lda) * (ACVT == 2 ? 2 : 4));
        float* frow = fout + (size_t)(m0 + a_r) * lda;

        auto stageB = [&](int kt, int buf) {
            #pragma unroll
            for (int p = 0; p < BN / 64; ++p)
                gload16(B + (size_t)(n0 + p * 64 + sr) * ldb + kt * 32 + sc,
                        &Bs[buf * BN * 32 + (p * 64 + sr) * 32 + sc]);
        };

        // prologue: A(kt0), A(kt0+1) regs; B(kt0)->buf0, B(kt0+1)->buf1
        AV hva = Arow[(kt0 * 32 + a_c) / 4];
        AV hvb = hva;
        stageB(kt0, 0);
        if (ktn > 1) { hvb = Arow[((kt0 + 1) * 32 + a_c) / 4]; stageB(kt0 + 1, 1); }
        if (ktn > 1) asm volatile("s_waitcnt vmcnt(4)" ::: "memory");
        else         asm volatile("s_waitcnt vmcnt(0)" ::: "memory");

        int curB = 0, stB = 2;   // t%3 and (t+2)%3
        for (int t = 0; t < ktn; ++t) {
            const int kt = kt0 + t;
            const int curA = t & 1;
            // process A(t): exp, f_div_C store, bf16 -> As[curA]
            AV v = hva; hva = hvb;
            float4 vf;
            if constexpr (ACVT == 2) {
                vf.x = h2f(v.x); vf.y = h2f(v.y); vf.z = h2f(v.z); vf.w = h2f(v.w);
            } else {
                vf.x = v.x; vf.y = v.y; vf.z = v.z; vf.w = v.w;
            }
            float4 e;
            e.x = expf(vf.x - rm) * rz; e.y = expf(vf.y - rm) * rz;
            e.z = expf(vf.z - rm) * rz; e.w = expf(vf.w - rm) * rz;
            *(float4*)(frow + kt * 32 + a_c) = e;   // f_div_C output (exactly once)
            short4 tq = make_short4(f2bf(e.x), f2bf(e.y), f2bf(e.z), f2bf(e.w));
            *(short4*)&As[curA * BM * 32 + a_r * 32 + a_c] = tq;
            if (t + 2 < ktn) hvb = Arow[((kt + 2) * 32 + a_c) / 4];   // 2-deep A prefetch

            // As[curA] visible to all waves; B(t) landed (prev iter's vmcnt)
            asm volatile("s_waitcnt lgkmcnt(0)\n\ts_barrier" ::: "memory");
            if (t + 2 < ktn) stageB(kt + 2, stB);

            bf16x8 af[MI], bfr[4];
            #pragma unroll
            for (int i = 0; i < MI; ++i)
                af[i] = *(bf16x8*)&As[curA * BM * 32 + (wrow + i * 16 + (lane & 15)) * 32 + (lane >> 4) * 8];
            #pragma unroll
            for (int j = 0; j < 4; ++j)
                bfr[j] = *(bf16x8*)&Bs[curB * BN * 32 + (wc * 64 + j * 16 + (lane & 15)) * 32 + (lane >> 4) * 8];
            __builtin_amdgcn_s_setprio(1);
            #pragma unroll
            for (int i = 0; i < MI; ++i)
                #pragma unroll
                for (int j = 0; j < 4; ++j)
                    acc[i][j] = __builtin_amdgcn_mfma_f32_16x16x32_bf16(af[i], bfr[j], acc[i][j], 0, 0, 0);
            __builtin_amdgcn_s_setprio(0);

            // drain B(t+1) only: newest-6 = {store(t), A(t+2), B(t+2)x4} stay in flight
            if (t + 2 < ktn)      asm volatile("s_waitcnt vmcnt(6)\n\ts_barrier" ::: "memory");
            else if (t + 1 < ktn) asm volatile("s_waitcnt vmcnt(1)\n\ts_barrier" ::: "memory");
            else                  asm volatile("s_waitcnt vmcnt(0)\n\ts_barrier" ::: "memory");
            curB = (curB == 2) ? 0 : curB + 1;
            stB  = (stB == 2) ? 0 : stB + 1;
        }
    }

    // epilogue: C/D layout col=lane&15, row=(lane>>4)*4+reg  [m89-verified]
    const int col = lane & 15, rowq = lane >> 4;

    if constexpr (EPI == 5 || EPI == 6) {
        // masked raw-P store + flash-style per-(row, colblock) stats
        __shared__ float sm[NWC][BM];
        __shared__ float ss[NWC][BM];
        int cbj[4];
        #pragma unroll
        for (int j = 0; j < 4; ++j)
            cbj[j] = (n0 + wc * 64 + j * 16 + col) / BLKSZ;
        #pragma unroll
        for (int i = 0; i < MI; ++i) {
            #pragma unroll
            for (int r = 0; r < 4; ++r) {
                const int trow = wrow + i * 16 + rowq * 4 + r;
                const int grow = m0 + trow;
                const int rb = grow / BLKSZ;
                float vj[4];
                float vmax = -1e30f;
                #pragma unroll
                for (int j = 0; j < 4; ++j) {
                    float v = acc[i][j][r];
                    if (cbj[j] == rb) v = -30000.0f;   // mask: exp underflows to 0
                    const size_t idx = (size_t)grow * Nn + (n0 + wc * 64 + j * 16 + col);
                    if constexpr (EPI == 6) {
                        unsigned short hh = f2h(v);
                        ((unsigned short*)Cvoid)[idx] = hh;
                        v = h2f(hh);       // stats from rounded value
                    } else {
                        ((float*)Cvoid)[idx] = v;
                    }
                    vj[j] = v;
                    vmax = fmaxf(vmax, v);
                }
                #pragma unroll
                for (int off = 1; off < 16; off <<= 1)
                    vmax = fmaxf(vmax, __shfl_xor(vmax, off));
                float s = 0.f;
                #pragma unroll
                for (int j = 0; j < 4; ++j) s += expf(vj[j] - vmax);
                #pragma unroll
                for (int off = 1; off < 16; off <<= 1)
                    s += __shfl_xor(s, off);
                if (col == 0) { sm[wc][trow] = vmax; ss[wc][trow] = s; }
            }
        }
        __syncthreads();
        if (tid < BM) {
            const float ma = sm[0][tid], mb = sm[1][tid];
            const float mx = fmaxf(ma, mb);
            const float S = ss[0][tid] * expf(ma - mx) + ss[1][tid] * expf(mb - mx);
            ((float2*)stats)[(size_t)bx * M + (m0 + tid)] = make_float2(mx, S);
        }
    } else if constexpr (EPI == 7) {
        if (n0 < 512) {
            // xcat bf16, ld 512, col-bias
            #pragma unroll
            for (int i = 0; i < MI; ++i)
                #pragma unroll
                for (int j = 0; j < 4; ++j)
                    #pragma unroll
                    for (int r = 0; r < 4; ++r) {
                        const int grow = m0 + wrow + i * 16 + rowq * 4 + r;
                        const int gcol = n0 + wc * 64 + j * 16 + col;
                        ((short*)Cvoid)[(size_t)grow * 512 + gcol] =
                            f2bf(acc[i][j][r] + bias[gcol]);
                    }
        } else {
            // transposed store into gxT (CI, T), col-bias
            short* gxTp = (short*)stats;
            #pragma unroll
            for (int i = 0; i < MI; ++i)
                #pragma unroll
                for (int j = 0; j < 4; ++j) {
                    const int grow0 = m0 + wrow + i * 16 + rowq * 4;
                    const int gcol = n0 + wc * 64 + j * 16 + col;
                    const float bv = bias[gcol];
                    short4 t = make_short4(
                        f2bf(acc[i][j][0] + bv), f2bf(acc[i][j][1] + bv),
                        f2bf(acc[i][j][2] + bv), f2bf(acc[i][j][3] + bv));
                    *(short4*)&gxTp[(size_t)(gcol - 512) * T_DIM + grow0] = t;
                }
        }
    } else {
        #pragma unroll
        for (int i = 0; i < MI; ++i) {
            #pragma unroll
            for (int j = 0; j < 4; ++j) {
                #pragma unroll
                for (int r = 0; r < 4; ++r) {
                    const int grow = m0 + wrow + i * 16 + rowq * 4 + r;
                    const int gcol = n0 + wc * 64 + j * 16 + col;
                    const float v = acc[i][j][r];
                    if (EPI == 1) {
                        ((short*)Cvoid)[(size_t)grow * Nn + gcol] = f2bf(v + bias[gcol]);
                    } else if (EPI == 2) {
                        ((short*)Cvoid)[(size_t)grow * Nn + gcol] = f2bf(v + bias[grow]);
                    } else if (EPI == 3) {
                        ((unsigned short*)Cvoid)[(size_t)blockIdx.z * M * Nn + (size_t)grow * Nn + gcol] = f2h(v);
                    } else {
                        const int nb = grow / BLKSZ, bb = grow - nb * BLKSZ;
                        ((float*)Cvoid)[(size_t)grow * Nn + gcol] =
                            v + bias[gcol] + ori[((size_t)nb * C_DIM + gcol) * BLKSZ + bb];
                    }
                }
            }
        }
    }
}

// ---------------------------------------------------------------------------
// Reduce split-K partials (ns, T, CI) fp16 -> y (T, CI) bf16.
// ---------------------------------------------------------------------------
__global__ __launch_bounds__(256) void reduce_y_kernel(
    const unsigned short* __restrict__ part, short* __restrict__ y, int ns)
{
    const size_t i = (size_t)blockIdx.x * 256 + threadIdx.x;  // ushort4 index
    float s0 = 0.f, s1 = 0.f, s2 = 0.f, s3 = 0.f;
    for (int z = 0; z < ns; ++z) {
        ushort4 v = *(const ushort4*)(part + (size_t)z * T_DIM * CI + i * 4);
        s0 += h2f(v.x); s1 += h2f(v.y); s2 += h2f(v.z); s3 += h2f(v.w);
    }
    short4 t = make_short4(f2bf(s0), f2bf(s1), f2bf(s2), f2bf(s3));
    *(short4*)(y + i * 4) = t;
}

// ---------------------------------------------------------------------------
extern "C" void kernel_launch(void* const* d_in, const int* in_sizes, int n_in,
                              void* d_out, int out_size, void* d_ws, size_t ws_size,
                              hipStream_t stream)
{
    const float* ori     = (const float*)d_in[0];
    const float* gamma   = (const float*)d_in[1];
    const float* beta    = (const float*)d_in[2];
    const float* mean    = (const float*)d_in[3];
    const float* var     = (const float*)d_in[4];
    const float* theta_w = (const float*)d_in[5];
    const float* theta_b = (const float*)d_in[6];
    const float* phi_w   = (const float*)d_in[7];
    const float* phi_b   = (const float*)d_in[8];
    const float* g_w     = (const float*)d_in[9];
    const float* g_b     = (const float*)d_in[10];
    const float* W_w     = (const float*)d_in[11];
    const float* W_b     = (const float*)d_in[12];

    float* out = (float*)d_out;                    // att_fea (T, C), then f_div_C (T, T)
    float* P   = out + (size_t)T_DIM * C_DIM;      // f_div_C region

    char* wsb = (char*)d_ws;
    short* feat = (short*)wsb;  wsb += (size_t)T_DIM * C_DIM * 2;   // 6.03 MB
    short* xcat = (short*)wsb;  wsb += (size_t)T_DIM * 512 * 2;     // 6.03 MB (xth|xph)
    short* gxT  = (short*)wsb;  wsb += (size_t)CI * T_DIM * 2;      // 3.01 MB (CI, T)
    short* wall = (short*)wsb;  wsb += (size_t)768 * C_DIM * 2;     // 0.79 MB
    short* wW   = (short*)wsb;  wsb += (size_t)C_DIM * CI * 2;
    float* bcat = (float*)wsb;  wsb += 768 * 4;
    short* ybf  = (short*)wsb;  wsb += (size_t)T_DIM * CI * 2;      // 3.01 MB
    float* stats = (float*)wsb; wsb += (size_t)NCB * T_DIM * 8;     // 2.17 MB (own region)

    const size_t base   = (size_t)(wsb - (char*)d_ws);
    const size_t p16sz  = (size_t)T_DIM * T_DIM * 2;                // 69.3 MB
    const size_t ypsz4  = 4u * (size_t)T_DIM * CI * 2u;             // 12.1 MB (fp16)
    const bool bigws = ws_size >= base + p16sz + ypsz4;

    // 1) fused prep: BN+ReLU+transpose -> feat bf16; weights -> bf16 + bcat
    prep_kernel<<<384, 256, 0, stream>>>(ori, gamma, beta, mean, var, feat,
                                         theta_w, phi_w, g_w, W_w,
                                         theta_b, phi_b, g_b, wall, wW, bcat);

    // 2) merged: [xth | xph | gx] = feat @ wall^T + bcat  (M=T, Nn=768, K=512)
    //    cols<512 -> xcat bf16 (ld 512); cols>=512 -> gxT transposed (CI, T)
    gemm_nt<7, 0, 64, 128, 3><<<dim3(6, T_DIM / 64), 256, 0, stream>>>(
        feat, wall, bcat, xcat, T_DIM, 768, C_DIM, C_DIM, C_DIM, 1, nullptr,
        (float*)gxT, nullptr, nullptr);

    if (bigws) {
        // --- fp16 raw-P path ---
        unsigned short* p16 = (unsigned short*)wsb;
        unsigned short* ypart = (unsigned short*)(wsb + p16sz);

        // 3) P16 = mask(xth @ xph^T) fp16 + softmax stats (XCD-swizzled)
        gemm_nt<6, 0, 128, 128, 2><<<dim3(T_DIM / 128, T_DIM / 128), 256, 0, stream>>>(
            xcat, xcat + CI, nullptr, p16, T_DIM, T_DIM, CI, 512, 512, 1, nullptr,
            stats, nullptr, nullptr);
        // 4) ypart[z] = softmax(P16) @ gxT^T, per-block stats merge + 2-deep
        //    pipelined fused-softmax staging; writes f_div_C fp32 (once each)
        gemm_nt<3, 2, 32, 256, 3><<<dim3(1, T_DIM / 32, 4), 256, 0, stream>>>(
            p16, gxT, nullptr, ypart, T_DIM, CI, T_DIM, T_DIM, T_DIM, 4, nullptr,
            stats, nullptr, P);
        reduce_y_kernel<<<(T_DIM * CI / 4) / 256, 256, 0, stream>>>(ypart, ybf, 4);
    } else {
        // --- fallback: fp32 raw P in out region, softmax in place ---
        unsigned short* ypart = (unsigned short*)wsb;
        const int ns = (ws_size >= base + ypsz4) ? 4 : 2;

        gemm_nt<5, 0, 128, 128, 2><<<dim3(T_DIM / 128, T_DIM / 128), 256, 0, stream>>>(
            xcat, xcat + CI, nullptr, P, T_DIM, T_DIM, CI, 512, 512, 1, nullptr,
            stats, nullptr, nullptr);
        gemm_nt<3, 1, 32, 256, 3><<<dim3(1, T_DIM / 32, ns), 256, 0, stream>>>(
            P, gxT, nullptr, ypart, T_DIM, CI, T_DIM, T_DIM, T_DIM, ns, nullptr,
            stats, nullptr, P);
        reduce_y_kernel<<<(T_DIM * CI / 4) / 256, 256, 0, stream>>>(ypart, ybf, ns);
    }

    // 6) att_fea = y @ wW^T + W_b + ori^T  (M=T, Nn=C, K=CI), fp32 out
    gemm_nt<4, 0, 64, 128, 3><<<dim3(C_DIM / 128, T_DIM / 64), 256, 0, stream>>>(
        ybf, wW, W_b, out, T_DIM, C_DIM, CI, CI, CI, 1, ori,
        nullptr, nullptr, nullptr);
}